// Round 8
// baseline (375015.259 us; speedup 1.0000x reference)
//
#include <hip/hip_runtime.h>
#include <math.h>

// 2-layer GRU, T=4096, B=64, H=512, input=1. Output = final hidden (2,64,512) f32.
//
// R8 = R7 with the spill fixed (R7: VGPR capped at 256 + 251 GB/dispatch
// scratch writes = whole runtime). Changes:
//   - __launch_bounds__(256, 1): 1 WG/CU by design -> allow up to 512 VGPR
//   - sched_barrier(0) every 8 k in FMA blocks: cap LDS-read hoisting window
// Structure (unchanged from R7): persistent, fence-free relaxed-agent atomics
// via LLC; software-pipelined 32-register load chunks; decoupled per-WG flags
// with depth-4 rings:
//   L0@t waits L0min>=t && L1min>=t-3 ; L1@t waits L0min>=t && L1min>=t-1
//   L0: WGs [0,64):  8 j per WG, wave w: k in [w*128,(w+1)*128)
//   L1: WGs [64,192): 4 j per WG, wave w: k in [w*256,(w+1)*256) of K=1024
// Rings: h state s in slot s&3. ws: hT0[4][512][64] | hT1[4][512][64] | flags

#define TT 4096
#define BB 64
#define HH 512
#define HB (HH * BB)
#define NWG 192
#define L0WG 64
#define PADU 32

__device__ __forceinline__ float sigm(float v) { return 1.0f / (1.0f + expf(-v)); }

__device__ __forceinline__ float aldf(const float* p) {
    return __hip_atomic_load((float*)p, __ATOMIC_RELAXED, __HIP_MEMORY_SCOPE_AGENT);
}
__device__ __forceinline__ void astf(float* p, float v) {
    __hip_atomic_store(p, v, __ATOMIC_RELAXED, __HIP_MEMORY_SCOPE_AGENT);
}
__device__ __forceinline__ unsigned aldu(const unsigned* p) {
    return __hip_atomic_load((unsigned*)p, __ATOMIC_RELAXED, __HIP_MEMORY_SCOPE_AGENT);
}
__device__ __forceinline__ void astu(unsigned* p, unsigned v) {
    __hip_atomic_store(p, v, __ATOMIC_RELAXED, __HIP_MEMORY_SCOPE_AGENT);
}

__global__ __launch_bounds__(256) void zero_k(float* p, int n) {
    int i = blockIdx.x * 256 + threadIdx.x;
    if (i < n) p[i] = 0.0f;
}

// wave0 polls: group0 (L0 flags, need0), groups 1-2 (L1 flags, need1).
__device__ __forceinline__ void wait_flags(unsigned* flags, int tid, int id,
                                           unsigned need0, unsigned need1) {
    if (tid < 64) {
        for (;;) {
            unsigned a = aldu(&flags[tid * PADU]);
            unsigned b = aldu(&flags[(64 + tid) * PADU]);
            unsigned c = aldu(&flags[(128 + tid) * PADU]);
            bool oka = (tid == id)       || (a >= need0);
            bool okb = (64 + tid == id)  || (b >= need1);
            bool okc = (128 + tid == id) || (c >= need1);
            if (__all(oka && okb && okc)) break;
            __builtin_amdgcn_s_sleep(1);
        }
    }
    __syncthreads();
    asm volatile("" ::: "memory");
}

__global__ __launch_bounds__(256, 1) void gru_persist(
    const float* __restrict__ x,
    const float* __restrict__ wih0, const float* __restrict__ whh0,
    const float* __restrict__ bih0, const float* __restrict__ bhh0,
    const float* __restrict__ wih1, const float* __restrict__ whh1,
    const float* __restrict__ bih1, const float* __restrict__ bhh1,
    float* __restrict__ ws)
{
    __shared__ float wlds[12288];   // 48 KB weights
    __shared__ float red[3072];     // 12 KB cross-wave reduction

    float* hT0 = ws;                         // [4][512][64]
    float* hT1 = ws + 4 * HB;                // [4][512][64]
    unsigned* flags = (unsigned*)(ws + 8 * HB);

    const int tid  = threadIdx.x;
    const int lane = tid & 63;               // batch index b
    const int w    = tid >> 6;               // wave 0..3
    const int id   = blockIdx.x;

    if (id < L0WG) {
        // ===================== Layer 0 =====================
        const int jg = id;
        for (int idx = tid; idx < 24 * 512; idx += 256) {
            int e = idx >> 9, k = idx & 511;
            int jl = e / 3, g = e - 3 * jl;
            wlds[k * 24 + e] = whh0[(size_t)(g * HH + jg * 8 + jl) * HH + k];
        }
        const int ja = jg * 8 + 2 * w, jb = ja + 1;
        const float wirA = wih0[ja], wizA = wih0[HH + ja], winA = wih0[2 * HH + ja];
        const float wirB = wih0[jb], wizB = wih0[HH + jb], winB = wih0[2 * HH + jb];
        const float brA = bih0[ja] + bhh0[ja];
        const float bzA = bih0[HH + ja] + bhh0[HH + ja];
        const float bnxA = bih0[2 * HH + ja], bnhA = bhh0[2 * HH + ja];
        const float brB = bih0[jb] + bhh0[jb];
        const float bzB = bih0[HH + jb] + bhh0[HH + jb];
        const float bnxB = bih0[2 * HH + jb], bnhB = bhh0[2 * HH + jb];
        const int kb = w * 128;
        __syncthreads();

        for (int t = 0; t < TT; ++t) {
            if (t >= 1) {
                unsigned need1 = (t >= 3) ? (unsigned)(t - 3) : 0u;
                wait_flags(flags, tid, id, (unsigned)t, need1);
            }
            const float* hin  = hT0 + ((t + 3) & 3) * HB;   // state t-1
            float*       hout = hT0 + (t & 3) * HB;         // state t
            const float* hbase = hin + lane;

            float hA[32], hB[32];
            #pragma unroll
            for (int i = 0; i < 32; ++i) hA[i] = aldf(hbase + (kb + i) * 64);
            float acc[24];
            #pragma unroll
            for (int e = 0; e < 24; ++e) acc[e] = 0.0f;

            #pragma unroll 1
            for (int c = 0; c < 2; ++c) {
                const int k0 = kb + c * 64;
                #pragma unroll
                for (int i = 0; i < 32; ++i) hB[i] = aldf(hbase + (k0 + 32 + i) * 64);
                #pragma unroll
                for (int g8 = 0; g8 < 4; ++g8) {
                    #pragma unroll
                    for (int u = 0; u < 8; ++u) {
                        const int i = g8 * 8 + u;
                        const float hv = hA[i];
                        const float4* wp = (const float4*)&wlds[(k0 + i) * 24];
                        const float4 q0 = wp[0], q1 = wp[1], q2 = wp[2];
                        const float4 q3 = wp[3], q4 = wp[4], q5 = wp[5];
                        acc[0] += q0.x * hv; acc[1] += q0.y * hv; acc[2] += q0.z * hv; acc[3] += q0.w * hv;
                        acc[4] += q1.x * hv; acc[5] += q1.y * hv; acc[6] += q1.z * hv; acc[7] += q1.w * hv;
                        acc[8] += q2.x * hv; acc[9] += q2.y * hv; acc[10] += q2.z * hv; acc[11] += q2.w * hv;
                        acc[12] += q3.x * hv; acc[13] += q3.y * hv; acc[14] += q3.z * hv; acc[15] += q3.w * hv;
                        acc[16] += q4.x * hv; acc[17] += q4.y * hv; acc[18] += q4.z * hv; acc[19] += q4.w * hv;
                        acc[20] += q5.x * hv; acc[21] += q5.y * hv; acc[22] += q5.z * hv; acc[23] += q5.w * hv;
                    }
                    __builtin_amdgcn_sched_barrier(0);
                }
                if (c < 1) {
                    #pragma unroll
                    for (int i = 0; i < 32; ++i) hA[i] = aldf(hbase + (k0 + 64 + i) * 64);
                }
                #pragma unroll
                for (int g8 = 0; g8 < 4; ++g8) {
                    #pragma unroll
                    for (int u = 0; u < 8; ++u) {
                        const int i = g8 * 8 + u;
                        const float hv = hB[i];
                        const float4* wp = (const float4*)&wlds[(k0 + 32 + i) * 24];
                        const float4 q0 = wp[0], q1 = wp[1], q2 = wp[2];
                        const float4 q3 = wp[3], q4 = wp[4], q5 = wp[5];
                        acc[0] += q0.x * hv; acc[1] += q0.y * hv; acc[2] += q0.z * hv; acc[3] += q0.w * hv;
                        acc[4] += q1.x * hv; acc[5] += q1.y * hv; acc[6] += q1.z * hv; acc[7] += q1.w * hv;
                        acc[8] += q2.x * hv; acc[9] += q2.y * hv; acc[10] += q2.z * hv; acc[11] += q2.w * hv;
                        acc[12] += q3.x * hv; acc[13] += q3.y * hv; acc[14] += q3.z * hv; acc[15] += q3.w * hv;
                        acc[16] += q4.x * hv; acc[17] += q4.y * hv; acc[18] += q4.z * hv; acc[19] += q4.w * hv;
                        acc[20] += q5.x * hv; acc[21] += q5.y * hv; acc[22] += q5.z * hv; acc[23] += q5.w * hv;
                    }
                    __builtin_amdgcn_sched_barrier(0);
                }
            }

            // cross-wave reduction, round 1: e 0..11 (jl 0..3)
            float4* r4 = (float4*)red;
            const int rb4 = (w * 64 + lane) * 3;
            r4[rb4 + 0] = make_float4(acc[0], acc[1], acc[2], acc[3]);
            r4[rb4 + 1] = make_float4(acc[4], acc[5], acc[6], acc[7]);
            r4[rb4 + 2] = make_float4(acc[8], acc[9], acc[10], acc[11]);
            __syncthreads();
            float sA0 = 0.f, sA1 = 0.f, sA2 = 0.f, sB0 = 0.f, sB1 = 0.f, sB2 = 0.f;
            if (w < 2) {
                #pragma unroll
                for (int wp_ = 0; wp_ < 4; ++wp_) {
                    const float* rb = &red[(wp_ * 64 + lane) * 12 + 6 * w];
                    sA0 += rb[0]; sA1 += rb[1]; sA2 += rb[2];
                    sB0 += rb[3]; sB1 += rb[4]; sB2 += rb[5];
                }
            }
            __syncthreads();
            // round 2: e 12..23 (jl 4..7)
            r4[rb4 + 0] = make_float4(acc[12], acc[13], acc[14], acc[15]);
            r4[rb4 + 1] = make_float4(acc[16], acc[17], acc[18], acc[19]);
            r4[rb4 + 2] = make_float4(acc[20], acc[21], acc[22], acc[23]);
            __syncthreads();
            if (w >= 2) {
                #pragma unroll
                for (int wp_ = 0; wp_ < 4; ++wp_) {
                    const float* rb = &red[(wp_ * 64 + lane) * 12 + 6 * (w - 2)];
                    sA0 += rb[0]; sA1 += rb[1]; sA2 += rb[2];
                    sB0 += rb[3]; sB1 += rb[4]; sB2 += rb[5];
                }
            }
            // epilogue: 2 outputs per thread
            const float xv = x[(size_t)t * BB + lane];
            const float holdA = aldf(&hin[ja * 64 + lane]);
            const float holdB = aldf(&hin[jb * 64 + lane]);
            {
                const float r = sigm(xv * wirA + brA + sA0);
                const float z = sigm(xv * wizA + bzA + sA1);
                const float n = tanhf(xv * winA + bnxA + r * (sA2 + bnhA));
                astf(&hout[ja * 64 + lane], (1.0f - z) * n + z * holdA);
            }
            {
                const float r = sigm(xv * wirB + brB + sB0);
                const float z = sigm(xv * wizB + bzB + sB1);
                const float n = tanhf(xv * winB + bnxB + r * (sB2 + bnhB));
                astf(&hout[jb * 64 + lane], (1.0f - z) * n + z * holdB);
            }
            __syncthreads();                    // all waves' stores drained
            if (tid == 0) astu(&flags[id * PADU], (unsigned)(t + 1));
        }
    } else {
        // ===================== Layer 1 =====================
        const int jg = id - L0WG;            // 0..127
        for (int idx = tid; idx < 12 * 1024; idx += 256) {
            int e = idx >> 10, k = idx & 1023;
            int jl = e / 3, g = e - 3 * jl;
            int row = g * HH + jg * 4 + jl;
            wlds[k * 12 + e] = (k < HH) ? wih1[(size_t)row * HH + k]
                                        : whh1[(size_t)row * HH + (k - HH)];
        }
        const int j = jg * 4 + w;
        const float br  = bih1[j] + bhh1[j];
        const float bz  = bih1[HH + j] + bhh1[HH + j];
        const float bnx = bih1[2 * HH + j], bnh = bhh1[2 * HH + j];
        const int kb = w * 256;
        __syncthreads();

        for (int t = 1; t <= TT; ++t) {       // computes state t-1
            wait_flags(flags, tid, id, (unsigned)t, (unsigned)(t - 1));
            const float* y0  = hT0 + ((t + 3) & 3) * HB;   // h0 state t-1
            const float* h1i = hT1 + ((t + 2) & 3) * HB;   // h1 state t-2
            float*       h1o = hT1 + ((t + 3) & 3) * HB;   // h1 state t-1
            const float* src = ((w < 2) ? y0 : h1i) + lane;
            const int koff = (w < 2) ? kb : (kb - 512);

            float hA[32], hB[32];
            #pragma unroll
            for (int i = 0; i < 32; ++i) hA[i] = aldf(src + (koff + i) * 64);
            float acc[12];
            #pragma unroll
            for (int e = 0; e < 12; ++e) acc[e] = 0.0f;

            #pragma unroll 1
            for (int c = 0; c < 4; ++c) {
                const int k0 = c * 64;
                #pragma unroll
                for (int i = 0; i < 32; ++i)
                    hB[i] = aldf(src + (koff + k0 + 32 + i) * 64);
                #pragma unroll
                for (int g8 = 0; g8 < 4; ++g8) {
                    #pragma unroll
                    for (int u = 0; u < 8; ++u) {
                        const int i = g8 * 8 + u;
                        const float hv = hA[i];
                        const float4* wp = (const float4*)&wlds[(kb + k0 + i) * 12];
                        const float4 q0 = wp[0], q1 = wp[1], q2 = wp[2];
                        acc[0] += q0.x * hv; acc[1] += q0.y * hv; acc[2] += q0.z * hv; acc[3] += q0.w * hv;
                        acc[4] += q1.x * hv; acc[5] += q1.y * hv; acc[6] += q1.z * hv; acc[7] += q1.w * hv;
                        acc[8] += q2.x * hv; acc[9] += q2.y * hv; acc[10] += q2.z * hv; acc[11] += q2.w * hv;
                    }
                    __builtin_amdgcn_sched_barrier(0);
                }
                if (c < 3) {
                    #pragma unroll
                    for (int i = 0; i < 32; ++i)
                        hA[i] = aldf(src + (koff + k0 + 64 + i) * 64);
                }
                #pragma unroll
                for (int g8 = 0; g8 < 4; ++g8) {
                    #pragma unroll
                    for (int u = 0; u < 8; ++u) {
                        const int i = g8 * 8 + u;
                        const float hv = hB[i];
                        const float4* wp = (const float4*)&wlds[(kb + k0 + 32 + i) * 12];
                        const float4 q0 = wp[0], q1 = wp[1], q2 = wp[2];
                        acc[0] += q0.x * hv; acc[1] += q0.y * hv; acc[2] += q0.z * hv; acc[3] += q0.w * hv;
                        acc[4] += q1.x * hv; acc[5] += q1.y * hv; acc[6] += q1.z * hv; acc[7] += q1.w * hv;
                        acc[8] += q2.x * hv; acc[9] += q2.y * hv; acc[10] += q2.z * hv; acc[11] += q2.w * hv;
                    }
                    __builtin_amdgcn_sched_barrier(0);
                }
            }

            // single-round cross-wave reduction
            float4* r4 = (float4*)red;
            const int rb4 = (w * 64 + lane) * 3;
            r4[rb4 + 0] = make_float4(acc[0], acc[1], acc[2], acc[3]);
            r4[rb4 + 1] = make_float4(acc[4], acc[5], acc[6], acc[7]);
            r4[rb4 + 2] = make_float4(acc[8], acc[9], acc[10], acc[11]);
            __syncthreads();
            float sr = 0.f, sz = 0.f, snx = 0.f, snh = 0.f;
            #pragma unroll
            for (int wp_ = 0; wp_ < 4; ++wp_) {
                const float* rb = &red[(wp_ * 64 + lane) * 12 + 3 * w];
                sr += rb[0]; sz += rb[1];
                if (wp_ < 2) snx += rb[2]; else snh += rb[2];
            }
            const float hold = aldf(&h1i[j * 64 + lane]);
            const float r = sigm(sr + br);
            const float z = sigm(sz + bz);
            const float n = tanhf(snx + bnx + r * (snh + bnh));
            astf(&h1o[j * 64 + lane], (1.0f - z) * n + z * hold);
            __syncthreads();                    // stores drained + red safe
            if (tid == 0) astu(&flags[id * PADU], (unsigned)t);
        }
    }
}

// out[l][b][j] = hTl[slot 3][j][b]  (state 4095, slot 4095&3 = 3)
__global__ __launch_bounds__(256) void copy_out_k(const float* __restrict__ ws,
                                                  float* __restrict__ out) {
    int i = blockIdx.x * 256 + threadIdx.x;
    int l = i >> 15;
    int r = i & 32767;
    int b = r >> 9;
    int j = r & 511;
    out[i] = ws[(size_t)l * 4 * HB + 3 * HB + j * 64 + b];
}

extern "C" void kernel_launch(void* const* d_in, const int* in_sizes, int n_in,
                              void* d_out, int out_size, void* d_ws, size_t ws_size,
                              hipStream_t stream)
{
    const float* x    = (const float*)d_in[0];
    const float* wih0 = (const float*)d_in[1];
    const float* whh0 = (const float*)d_in[2];
    const float* bih0 = (const float*)d_in[3];
    const float* bhh0 = (const float*)d_in[4];
    const float* wih1 = (const float*)d_in[5];
    const float* whh1 = (const float*)d_in[6];
    const float* bih1 = (const float*)d_in[7];
    const float* bhh1 = (const float*)d_in[8];
    float* out = (float*)d_out;
    float* ws  = (float*)d_ws;

    const int nzero = 8 * HB + NWG * PADU;   // rings (4-deep x2) + flags
    zero_k<<<(nzero + 255) / 256, 256, 0, stream>>>(ws, nzero);
    gru_persist<<<NWG, 256, 0, stream>>>(x, wih0, whh0, bih0, bhh0,
                                         wih1, whh1, bih1, bhh1, ws);
    copy_out_k<<<(2 * BB * HH) / 256, 256, 0, stream>>>(ws, out);
}

// Round 9
// 52280.835 us; speedup vs baseline: 7.1731x; 7.1731x over previous
//
#include <hip/hip_runtime.h>
#include <math.h>

// 2-layer GRU, T=4096, B=64, H=512, input=1. Output = final hidden (2,64,512) f32.
//
// R9: bf16-SPLIT MFMA rewrite. R6/R8 analysis: fp32 VALU path is DS-pipe-bound
// (weight broadcast b128 ~12cy, 3072/WG/step = ~18us/step floor). Fix: MFMA
// 16x16x32_bf16 with split operands (hi+lo bf16; D = Ah*Bh + Ah*Bl + Al*Bh,
// fp32 acc => ~2^-17 per-product precision).
//  - weights pre-split into A-frag layout (init kernel, ws ~9MB), streamed as
//    ordinary cached dwordx4 loads (read-only, L2-resident). NO LDS anywhere.
//  - h rings store packed u32 (bf16hi<<16 | bf16lo); B-frags = 8 coherent
//    dword loads + v_perm pairs. Coherence = relaxed agent atomics (R6-proven).
//  - 64 WGs: 32 L0 + 32 L1, one 16-wide j-tile each (3 gate row-tiles x 64 b
//    x full K); wave = b-tile. Decoupled per-WG flags (R7-proven):
//      L0@t waits L0>=t && L1>=t-3 ; L1@t waits L0>=t && L1>=t-1
//  - L1 n-gate: separate accNX (k<512, x-side) / accNH (k>=512, h-side).
// ws: ring0[4][512][64]u32 | ring1[...] | flags[64*32] | aw0 bf16[1.57M] | aw1 bf16[3.15M]

#define TT 4096
#define BB 64
#define HH 512
#define NWG 64
#define L0WG 32
#define PADU 32
#define HB32 (HH * BB)   // u32 per ring slot

typedef __attribute__((ext_vector_type(8))) short bf16x8;
typedef __attribute__((ext_vector_type(4))) float f32x4;

#define MFMA16(a, b, c) __builtin_amdgcn_mfma_f32_16x16x32_bf16((a), (b), (c), 0, 0, 0)

__device__ __forceinline__ float sigm(float v) { return 1.0f / (1.0f + expf(-v)); }

__device__ __forceinline__ unsigned aldu(const unsigned* p) {
    return __hip_atomic_load((unsigned*)p, __ATOMIC_RELAXED, __HIP_MEMORY_SCOPE_AGENT);
}
__device__ __forceinline__ void astu(unsigned* p, unsigned v) {
    __hip_atomic_store(p, v, __ATOMIC_RELAXED, __HIP_MEMORY_SCOPE_AGENT);
}
__device__ __forceinline__ unsigned short rneb(float f) {   // fp32 -> bf16 RNE
    unsigned u = __float_as_uint(f);
    return (unsigned short)((u + 0x7fffu + ((u >> 16) & 1u)) >> 16);
}
__device__ __forceinline__ float bfhi_f(unsigned p) { return __uint_as_float(p & 0xffff0000u); }
__device__ __forceinline__ float bflo_f(unsigned p) { return __uint_as_float(p << 16); }

union frag_u { unsigned u[4]; bf16x8 v; };
__device__ __forceinline__ bf16x8 mkfrag(unsigned a, unsigned b, unsigned c, unsigned d) {
    frag_u x; x.u[0] = a; x.u[1] = b; x.u[2] = c; x.u[3] = d; return x.v;
}

__global__ __launch_bounds__(256) void zero_k(unsigned* p, int n) {
    int i = blockIdx.x * 256 + threadIdx.x;
    if (i < n) p[i] = 0u;
}

// A-frag prep. Layout: frag f = ((rt*KTN + kt)*2 + split)*64 + lane holds 8 bf16:
// row = (rt&31)*16 + (lane&15) within gate rt>>5 ; k = kt*32 + (lane>>4)*8 + i.
__global__ __launch_bounds__(256) void prep_aw0(const float* __restrict__ whh0,
                                                unsigned short* __restrict__ aw0) {
    int gid = blockIdx.x * 256 + threadIdx.x;           // 96*16*2*64 = 196608
    if (gid >= 96 * 16 * 2 * 64) return;
    int lane = gid & 63, split = (gid >> 6) & 1, kt = (gid >> 7) & 15, rt = gid >> 11;
    int grow = (rt >> 5) * 512 + (rt & 31) * 16 + (lane & 15);
    int k0 = kt * 32 + (lane >> 4) * 8;
    #pragma unroll
    for (int i = 0; i < 8; ++i) {
        float val = whh0[(size_t)grow * 512 + k0 + i];
        unsigned short hb = rneb(val);
        unsigned short us = hb;
        if (split) us = rneb(val - __uint_as_float(((unsigned)hb) << 16));
        aw0[(size_t)gid * 8 + i] = us;
    }
}

__global__ __launch_bounds__(256) void prep_aw1(const float* __restrict__ wih1,
                                                const float* __restrict__ whh1,
                                                unsigned short* __restrict__ aw1) {
    int gid = blockIdx.x * 256 + threadIdx.x;           // 96*32*2*64 = 393216
    if (gid >= 96 * 32 * 2 * 64) return;
    int lane = gid & 63, split = (gid >> 6) & 1, kt = (gid >> 7) & 31, rt = gid >> 12;
    int grow = (rt >> 5) * 512 + (rt & 31) * 16 + (lane & 15);
    #pragma unroll
    for (int i = 0; i < 8; ++i) {
        int k = kt * 32 + (lane >> 4) * 8 + i;
        float val = (k < 512) ? wih1[(size_t)grow * 512 + k]
                              : whh1[(size_t)grow * 512 + (k - 512)];
        unsigned short hb = rneb(val);
        unsigned short us = hb;
        if (split) us = rneb(val - __uint_as_float(((unsigned)hb) << 16));
        aw1[(size_t)gid * 8 + i] = us;
    }
}

__device__ __forceinline__ void wait_flags(unsigned* flags, int tid,
                                           unsigned need0, unsigned need1) {
    if (tid < 64) {
        unsigned need = (tid < L0WG) ? need0 : need1;
        for (;;) {
            unsigned f = aldu(&flags[tid * PADU]);
            if (__all(f >= need)) break;
            __builtin_amdgcn_s_sleep(1);
        }
    }
    __syncthreads();
    asm volatile("" ::: "memory");
}

// build Bh/Bl frags from 8 packed u32 (hi<<16|lo)
#define LOAD_B(bp)                                                              \
    unsigned p0 = aldu((bp) + 0 * 64), p1 = aldu((bp) + 1 * 64);                \
    unsigned p2 = aldu((bp) + 2 * 64), p3 = aldu((bp) + 3 * 64);                \
    unsigned p4 = aldu((bp) + 4 * 64), p5 = aldu((bp) + 5 * 64);                \
    unsigned p6 = aldu((bp) + 6 * 64), p7 = aldu((bp) + 7 * 64);                \
    bf16x8 Bh = mkfrag(__builtin_amdgcn_perm(p1, p0, 0x07060302u),              \
                       __builtin_amdgcn_perm(p3, p2, 0x07060302u),              \
                       __builtin_amdgcn_perm(p5, p4, 0x07060302u),              \
                       __builtin_amdgcn_perm(p7, p6, 0x07060302u));             \
    bf16x8 Bl = mkfrag(__builtin_amdgcn_perm(p1, p0, 0x05040100u),              \
                       __builtin_amdgcn_perm(p3, p2, 0x05040100u),              \
                       __builtin_amdgcn_perm(p5, p4, 0x05040100u),              \
                       __builtin_amdgcn_perm(p7, p6, 0x05040100u));

#define GATE3(accv, g, kt, KTN)                                                 \
    {                                                                           \
        int fb = ((((g) * 32 + jt) * (KTN) + (kt)) * 2) * 64 + l;               \
        bf16x8 Ah = awf[fb];                                                    \
        bf16x8 Al = awf[fb + 64];                                               \
        accv = MFMA16(Ah, Bh, accv);                                            \
        accv = MFMA16(Ah, Bl, accv);                                            \
        accv = MFMA16(Al, Bh, accv);                                            \
    }

__global__ __launch_bounds__(256, 1) void gru_persist(
    const float* __restrict__ x,
    const float* __restrict__ wih0,
    const float* __restrict__ bih0, const float* __restrict__ bhh0,
    const float* __restrict__ bih1, const float* __restrict__ bhh1,
    unsigned* __restrict__ ws)
{
    unsigned* r0 = ws;                       // [4][512][64] packed
    unsigned* r1 = ws + 4 * HB32;
    unsigned* flags = ws + 8 * HB32;
    const unsigned short* aw0 = (const unsigned short*)(ws + 8 * HB32 + NWG * PADU);
    const unsigned short* aw1 = aw0 + (size_t)96 * 16 * 2 * 64 * 8;

    const int tid = threadIdx.x;
    const int l   = tid & 63;                // MFMA lane
    const int wv  = tid >> 6;                // wave = b-tile
    const int id  = blockIdx.x;
    const int bcol = wv * 16 + (l & 15);     // batch column this lane owns in C

    if (id < L0WG) {
        // ===================== Layer 0 (K=512, 16 k-tiles) =====================
        const int jt = id;
        float wir[4], wiz[4], win[4], br[4], bz[4], bnx[4], bnh[4];
        #pragma unroll
        for (int rg = 0; rg < 4; ++rg) {
            int jj = jt * 16 + (l >> 4) * 4 + rg;
            wir[rg] = wih0[jj]; wiz[rg] = wih0[512 + jj]; win[rg] = wih0[1024 + jj];
            br[rg]  = bih0[jj] + bhh0[jj];
            bz[rg]  = bih0[512 + jj] + bhh0[512 + jj];
            bnx[rg] = bih0[1024 + jj];
            bnh[rg] = bhh0[1024 + jj];
        }
        const bf16x8* awf = (const bf16x8*)aw0;

        for (int t = 0; t < TT; ++t) {
            if (t >= 1) {
                unsigned need1 = (t >= 3) ? (unsigned)(t - 3) : 0u;
                wait_flags(flags, tid, (unsigned)t, need1);
            }
            const unsigned* hin = r0 + ((t + 3) & 3) * HB32;   // state t-1
            unsigned*       hout = r0 + (t & 3) * HB32;        // state t
            f32x4 aR = {0.f, 0.f, 0.f, 0.f};
            f32x4 aZ = {0.f, 0.f, 0.f, 0.f};
            f32x4 aN = {0.f, 0.f, 0.f, 0.f};
            #pragma unroll 2
            for (int kt = 0; kt < 16; ++kt) {
                const unsigned* bp = hin + (kt * 32 + (l >> 4) * 8) * 64 + bcol;
                LOAD_B(bp)
                GATE3(aR, 0, kt, 16)
                GATE3(aZ, 1, kt, 16)
                GATE3(aN, 2, kt, 16)
            }
            const float xv = x[(size_t)t * BB + bcol];
            #pragma unroll
            for (int rg = 0; rg < 4; ++rg) {
                int jj = jt * 16 + (l >> 4) * 4 + rg;
                unsigned pold = aldu(hin + jj * 64 + bcol);
                float hold = bfhi_f(pold) + bflo_f(pold);
                float r = sigm(xv * wir[rg] + br[rg] + aR[rg]);
                float z = sigm(xv * wiz[rg] + bz[rg] + aZ[rg]);
                float n = tanhf(xv * win[rg] + bnx[rg] + r * (aN[rg] + bnh[rg]));
                float hn = (1.0f - z) * n + z * hold;
                unsigned hb = rneb(hn);
                unsigned lb = rneb(hn - __uint_as_float(hb << 16));
                astu(hout + jj * 64 + bcol, (hb << 16) | lb);
            }
            __syncthreads();                 // drains all waves' stores
            if (tid == 0) astu(&flags[id * PADU], (unsigned)(t + 1));
        }
    } else {
        // ===================== Layer 1 (K=1024, 32 k-tiles) =====================
        const int jt = id - L0WG;
        float br[4], bz[4], bnx[4], bnh[4];
        #pragma unroll
        for (int rg = 0; rg < 4; ++rg) {
            int jj = jt * 16 + (l >> 4) * 4 + rg;
            br[rg]  = bih1[jj] + bhh1[jj];
            bz[rg]  = bih1[512 + jj] + bhh1[512 + jj];
            bnx[rg] = bih1[1024 + jj];
            bnh[rg] = bhh1[1024 + jj];
        }
        const bf16x8* awf = (const bf16x8*)aw1;

        for (int t = 1; t <= TT; ++t) {      // computes h1 state t-1
            wait_flags(flags, tid, (unsigned)t, (unsigned)(t - 1));
            const unsigned* y0  = r0 + ((t + 3) & 3) * HB32;   // h0 state t-1
            const unsigned* h1p = r1 + ((t + 2) & 3) * HB32;   // h1 state t-2
            unsigned*       h1o = r1 + ((t + 3) & 3) * HB32;   // h1 state t-1
            f32x4 aR  = {0.f, 0.f, 0.f, 0.f};
            f32x4 aZ  = {0.f, 0.f, 0.f, 0.f};
            f32x4 aNX = {0.f, 0.f, 0.f, 0.f};
            f32x4 aNH = {0.f, 0.f, 0.f, 0.f};
            #pragma unroll 2
            for (int kt = 0; kt < 16; ++kt) {                  // x-side: y0
                const unsigned* bp = y0 + (kt * 32 + (l >> 4) * 8) * 64 + bcol;
                LOAD_B(bp)
                GATE3(aR, 0, kt, 32)
                GATE3(aZ, 1, kt, 32)
                GATE3(aNX, 2, kt, 32)
            }
            #pragma unroll 2
            for (int kt = 16; kt < 32; ++kt) {                 // h-side: h1
                const unsigned* bp = h1p + ((kt - 16) * 32 + (l >> 4) * 8) * 64 + bcol;
                LOAD_B(bp)
                GATE3(aR, 0, kt, 32)
                GATE3(aZ, 1, kt, 32)
                GATE3(aNH, 2, kt, 32)
            }
            #pragma unroll
            for (int rg = 0; rg < 4; ++rg) {
                int jj = jt * 16 + (l >> 4) * 4 + rg;
                unsigned pold = aldu(h1p + jj * 64 + bcol);
                float hold = bfhi_f(pold) + bflo_f(pold);
                float r = sigm(aR[rg] + br[rg]);
                float z = sigm(aZ[rg] + bz[rg]);
                float n = tanhf(aNX[rg] + bnx[rg] + r * (aNH[rg] + bnh[rg]));
                float hn = (1.0f - z) * n + z * hold;
                unsigned hb = rneb(hn);
                unsigned lb = rneb(hn - __uint_as_float(hb << 16));
                astu(h1o + jj * 64 + bcol, (hb << 16) | lb);
            }
            __syncthreads();
            if (tid == 0) astu(&flags[id * PADU], (unsigned)t);
        }
    }
}

// out[l][b][j] = f32(ring_l[slot3][j][b])  (state 4095 lives in slot 3 for both)
__global__ __launch_bounds__(256) void copy_out_k(const unsigned* __restrict__ ws,
                                                  float* __restrict__ out) {
    int i = blockIdx.x * 256 + threadIdx.x;   // 2*64*512 = 65536
    int lyr = i >> 15;
    int rem = i & 32767;
    int b = rem >> 9;
    int j = rem & 511;
    unsigned p = ws[(size_t)lyr * 4 * HB32 + 3 * HB32 + j * 64 + b];
    out[i] = bfhi_f(p) + bflo_f(p);
}

extern "C" void kernel_launch(void* const* d_in, const int* in_sizes, int n_in,
                              void* d_out, int out_size, void* d_ws, size_t ws_size,
                              hipStream_t stream)
{
    const float* x    = (const float*)d_in[0];
    const float* wih0 = (const float*)d_in[1];
    const float* whh0 = (const float*)d_in[2];
    const float* bih0 = (const float*)d_in[3];
    const float* bhh0 = (const float*)d_in[4];
    const float* wih1 = (const float*)d_in[5];
    const float* whh1 = (const float*)d_in[6];
    const float* bih1 = (const float*)d_in[7];
    const float* bhh1 = (const float*)d_in[8];
    float* out = (float*)d_out;
    unsigned* ws = (unsigned*)d_ws;

    unsigned short* aw0 = (unsigned short*)(ws + 8 * HB32 + NWG * PADU);
    unsigned short* aw1 = aw0 + (size_t)96 * 16 * 2 * 64 * 8;

    // zero rings + flags (rings = packed 0 => h = 0)
    const int nzero = 8 * HB32 + NWG * PADU;
    zero_k<<<(nzero + 255) / 256, 256, 0, stream>>>(ws, nzero);
    prep_aw0<<<(96 * 16 * 2 * 64) / 256, 256, 0, stream>>>(whh0, aw0);
    prep_aw1<<<(96 * 32 * 2 * 64) / 256, 256, 0, stream>>>(wih1, whh1, aw1);
    gru_persist<<<NWG, 256, 0, stream>>>(x, wih0, bih0, bhh0, bih1, bhh1, ws);
    copy_out_k<<<(2 * BB * HH) / 256, 256, 0, stream>>>(ws, out);
}

// Round 10
// 30487.369 us; speedup vs baseline: 12.3007x; 1.7148x over previous
//
#include <hip/hip_runtime.h>
#include <math.h>

// 2-layer GRU, T=4096, B=64, H=512, input=1. Output = final hidden (2,64,512) f32.
//
// R10: weights-in-registers MFMA. R9 diagnosis: 10us/step of LLC-latency
// stall (shallow load pipeline at 64 VGPR) + 9.4MB/step weight re-stream.
// Fix: 512-thread WGs (8 waves), wave = k-slice; each lane holds its A-frags
// permanently in VGPRs (L1: 96, L0: 48). Per-step loop = B loads + MFMAs only,
// fully unrolled/static. Cross-wave reduce via 64KB LDS (2 rounds; L1 keeps
// nx (waves 0-3, x-side) and nh (waves 4-7, h-side) in separate slots).
// Flag polls register-cache monotone values (skip LLC load when satisfied).
// Geometry: 64 WGs = 32 L0 + 32 L1, one 16-row j-tile each, 64 b columns.
//   L0 wave w: kt in {2w, 2w+1} of 16 (K=512)
//   L1 wave w: kt in {4w..4w+3} of 32 (K=1024: kt<16 x-side y0, >=16 h-side h1)
// Rings depth 4 (state s in slot s&3), decoupled flags (R7/R9-proven):
//   L0@t waits L0>=t && L1>=t-3 ; L1@t waits L0>=t && L1>=t-1
// ws: ring0[4][512][64]u32 | ring1[...] | flags[64*32] | aw0 | aw1

#define TT 4096
#define BB 64
#define HH 512
#define NWG 64
#define L0WG 32
#define PADU 32
#define HB32 (HH * BB)

typedef __attribute__((ext_vector_type(8))) short bf16x8;
typedef __attribute__((ext_vector_type(4))) float f32x4;

#define MFMA16(a, b, c) __builtin_amdgcn_mfma_f32_16x16x32_bf16((a), (b), (c), 0, 0, 0)

__device__ __forceinline__ float sigm(float v) { return 1.0f / (1.0f + expf(-v)); }

__device__ __forceinline__ unsigned aldu(const unsigned* p) {
    return __hip_atomic_load((unsigned*)p, __ATOMIC_RELAXED, __HIP_MEMORY_SCOPE_AGENT);
}
__device__ __forceinline__ void astu(unsigned* p, unsigned v) {
    __hip_atomic_store(p, v, __ATOMIC_RELAXED, __HIP_MEMORY_SCOPE_AGENT);
}
__device__ __forceinline__ unsigned short rneb(float f) {   // fp32 -> bf16 RNE
    unsigned u = __float_as_uint(f);
    return (unsigned short)((u + 0x7fffu + ((u >> 16) & 1u)) >> 16);
}
__device__ __forceinline__ float bfhi_f(unsigned p) { return __uint_as_float(p & 0xffff0000u); }
__device__ __forceinline__ float bflo_f(unsigned p) { return __uint_as_float(p << 16); }

union frag_u { unsigned u[4]; bf16x8 v; };
__device__ __forceinline__ bf16x8 mkfrag(unsigned a, unsigned b, unsigned c, unsigned d) {
    frag_u x; x.u[0] = a; x.u[1] = b; x.u[2] = c; x.u[3] = d; return x.v;
}

__global__ __launch_bounds__(256) void zero_k(unsigned* p, int n) {
    int i = blockIdx.x * 256 + threadIdx.x;
    if (i < n) p[i] = 0u;
}

// A-frag prep (R9 layout, verified): frag fb = ((rt*KTN + kt)*2 + split)*64 + lane,
// rt = gate*32 + jt; row = jt*16 + (lane&15); k = kt*32 + (lane>>4)*8 + i.
__global__ __launch_bounds__(256) void prep_aw0(const float* __restrict__ whh0,
                                                unsigned short* __restrict__ aw0) {
    int gid = blockIdx.x * 256 + threadIdx.x;           // 96*16*2*64
    if (gid >= 96 * 16 * 2 * 64) return;
    int lane = gid & 63, split = (gid >> 6) & 1, kt = (gid >> 7) & 15, rt = gid >> 11;
    int grow = (rt >> 5) * 512 + (rt & 31) * 16 + (lane & 15);
    int k0 = kt * 32 + (lane >> 4) * 8;
    #pragma unroll
    for (int i = 0; i < 8; ++i) {
        float val = whh0[(size_t)grow * 512 + k0 + i];
        unsigned short hb = rneb(val);
        unsigned short us = hb;
        if (split) us = rneb(val - __uint_as_float(((unsigned)hb) << 16));
        aw0[(size_t)gid * 8 + i] = us;
    }
}

__global__ __launch_bounds__(256) void prep_aw1(const float* __restrict__ wih1,
                                                const float* __restrict__ whh1,
                                                unsigned short* __restrict__ aw1) {
    int gid = blockIdx.x * 256 + threadIdx.x;           // 96*32*2*64
    if (gid >= 96 * 32 * 2 * 64) return;
    int lane = gid & 63, split = (gid >> 6) & 1, kt = (gid >> 7) & 31, rt = gid >> 12;
    int grow = (rt >> 5) * 512 + (rt & 31) * 16 + (lane & 15);
    #pragma unroll
    for (int i = 0; i < 8; ++i) {
        int k = kt * 32 + (lane >> 4) * 8 + i;
        float val = (k < 512) ? wih1[(size_t)grow * 512 + k]
                              : whh1[(size_t)grow * 512 + (k - 512)];
        unsigned short hb = rneb(val);
        unsigned short us = hb;
        if (split) us = rneb(val - __uint_as_float(((unsigned)hb) << 16));
        aw1[(size_t)gid * 8 + i] = us;
    }
}

// build Bh/Bl frags from 8 packed u32 (hi<<16|lo) at bp, bp+64, ...
#define LOAD_B(bp)                                                              \
    unsigned p0 = aldu((bp) + 0 * 64), p1 = aldu((bp) + 1 * 64);                \
    unsigned p2 = aldu((bp) + 2 * 64), p3 = aldu((bp) + 3 * 64);                \
    unsigned p4 = aldu((bp) + 4 * 64), p5 = aldu((bp) + 5 * 64);                \
    unsigned p6 = aldu((bp) + 6 * 64), p7 = aldu((bp) + 7 * 64);                \
    bf16x8 Bh = mkfrag(__builtin_amdgcn_perm(p1, p0, 0x07060302u),              \
                       __builtin_amdgcn_perm(p3, p2, 0x07060302u),              \
                       __builtin_amdgcn_perm(p5, p4, 0x07060302u),              \
                       __builtin_amdgcn_perm(p7, p6, 0x07060302u));             \
    bf16x8 Bl = mkfrag(__builtin_amdgcn_perm(p1, p0, 0x05040100u),              \
                       __builtin_amdgcn_perm(p3, p2, 0x05040100u),              \
                       __builtin_amdgcn_perm(p5, p4, 0x05040100u),              \
                       __builtin_amdgcn_perm(p7, p6, 0x05040100u));

__global__ __launch_bounds__(512, 1) void gru_persist(
    const float* __restrict__ x,
    const float* __restrict__ wih0,
    const float* __restrict__ bih0, const float* __restrict__ bhh0,
    const float* __restrict__ bih1, const float* __restrict__ bhh1,
    unsigned* __restrict__ ws)
{
    __shared__ float red[4][16][256];        // 64 KB: [pair][gate*4+bt][lane*4+rg]

    unsigned* r0 = ws;                        // [4][512][64] packed u32
    unsigned* r1 = ws + 4 * HB32;
    unsigned* flags = ws + 8 * HB32;
    const bf16x8* aw0f = (const bf16x8*)(ws + 8 * HB32 + NWG * PADU);
    const bf16x8* aw1f = aw0f + (size_t)96 * 16 * 2 * 64;

    const int tid = threadIdx.x;
    const int l   = tid & 63;
    const int w   = tid >> 6;                 // wave 0..7 = k-slice
    const int id  = blockIdx.x;

    // epilogue mapping: thread handles outputs (jl_e, b0) and (jl_e, b0+1)
    const int idx0 = tid * 2;                 // 0..1022 (even)
    const int jl_e = idx0 >> 6;               // 0..15
    const int b0   = idx0 & 63;               // even
    const int rg_e = jl_e & 3;
    const int li0  = ((jl_e >> 2) << 4) | b0; // b0<16 per-tile col handled via bt below
    // note: li uses (b & 15); recompute cleanly:
    const int lp_e = (jl_e >> 2) << 4;
    const int bt_e = b0 >> 4;
    const int lA = lp_e | (b0 & 15);          // lane index for b0
    const int lB = lA + 1;                    // b0+1 (b0 even => same bt, +1 lane col)
    (void)li0;

    unsigned fcache = 0;                      // cached flag value for flags[tid] (wave 0)

    if (id < L0WG) {
        // ===================== Layer 0 (K=512; wave w: kt = 2w,2w+1) =====================
        const int jt = id;
        bf16x8 wA[2][3][2];
        #pragma unroll
        for (int kk = 0; kk < 2; ++kk)
            #pragma unroll
            for (int g = 0; g < 3; ++g)
                #pragma unroll
                for (int s = 0; s < 2; ++s)
                    wA[kk][g][s] = aw0f[(size_t)(((g * 32 + jt) * 16 + (2 * w + kk)) * 2 + s) * 64 + l];

        const int jj = jt * 16 + jl_e;
        const float wir = wih0[jj], wiz = wih0[512 + jj], win = wih0[1024 + jj];
        const float br  = bih0[jj] + bhh0[jj];
        const float bz  = bih0[512 + jj] + bhh0[512 + jj];
        const float bnx = bih0[1024 + jj], bnh = bhh0[1024 + jj];

        for (int t = 0; t < TT; ++t) {
            if (t >= 1) {
                const unsigned need0 = (unsigned)t;
                const unsigned need1 = (t >= 3) ? (unsigned)(t - 3) : 0u;
                if (tid < 64) {
                    unsigned need = (tid == id) ? 0u : ((tid < L0WG) ? need0 : need1);
                    while (fcache < need) {
                        fcache = aldu(&flags[tid * PADU]);
                        if (fcache < need) __builtin_amdgcn_s_sleep(1);
                    }
                }
                __syncthreads();
            }
            const unsigned* hin  = r0 + ((t + 3) & 3) * HB32;
            unsigned*       hout = r0 + (t & 3) * HB32;

            f32x4 acc[3][4];
            #pragma unroll
            for (int g = 0; g < 3; ++g)
                #pragma unroll
                for (int bt = 0; bt < 4; ++bt)
                    acc[g][bt] = (f32x4){0.f, 0.f, 0.f, 0.f};

            #pragma unroll
            for (int kk = 0; kk < 2; ++kk) {
                const int kt = 2 * w + kk;
                #pragma unroll
                for (int bt = 0; bt < 4; ++bt) {
                    const unsigned* bp = hin + (kt * 32 + (l >> 4) * 8) * 64 + bt * 16 + (l & 15);
                    LOAD_B(bp)
                    #pragma unroll
                    for (int g = 0; g < 3; ++g) {
                        acc[g][bt] = MFMA16(wA[kk][g][0], Bh, acc[g][bt]);
                        acc[g][bt] = MFMA16(wA[kk][g][0], Bl, acc[g][bt]);
                        acc[g][bt] = MFMA16(wA[kk][g][1], Bh, acc[g][bt]);
                    }
                }
            }

            // reduce: round 1 (waves 0-3 write), round 2 (waves 4-7 add)
            if (w < 4) {
                #pragma unroll
                for (int g = 0; g < 3; ++g)
                    #pragma unroll
                    for (int bt = 0; bt < 4; ++bt)
                        *(f32x4*)&red[w][g * 4 + bt][l * 4] = acc[g][bt];
            }
            __syncthreads();
            if (w >= 4) {
                const int p = w - 4;
                #pragma unroll
                for (int g = 0; g < 3; ++g)
                    #pragma unroll
                    for (int bt = 0; bt < 4; ++bt) {
                        f32x4 v = *(f32x4*)&red[p][g * 4 + bt][l * 4];
                        v += acc[g][bt];
                        *(f32x4*)&red[p][g * 4 + bt][l * 4] = v;
                    }
            }
            __syncthreads();

            // epilogue: 2 outputs (jj, b0), (jj, b0+1)
            float sr0 = 0.f, sz0 = 0.f, sn0 = 0.f, sr1 = 0.f, sz1 = 0.f, sn1 = 0.f;
            #pragma unroll
            for (int p = 0; p < 4; ++p) {
                sr0 += red[p][0 * 4 + bt_e][lA * 4 + rg_e];
                sz0 += red[p][1 * 4 + bt_e][lA * 4 + rg_e];
                sn0 += red[p][2 * 4 + bt_e][lA * 4 + rg_e];
                sr1 += red[p][0 * 4 + bt_e][lB * 4 + rg_e];
                sz1 += red[p][1 * 4 + bt_e][lB * 4 + rg_e];
                sn1 += red[p][2 * 4 + bt_e][lB * 4 + rg_e];
            }
            const float xv0 = x[(size_t)t * BB + b0];
            const float xv1 = x[(size_t)t * BB + b0 + 1];
            unsigned po0 = aldu(hin + jj * 64 + b0);
            unsigned po1 = aldu(hin + jj * 64 + b0 + 1);
            {
                float r = sigm(xv0 * wir + br + sr0);
                float z = sigm(xv0 * wiz + bz + sz0);
                float n = tanhf(xv0 * win + bnx + r * (sn0 + bnh));
                float hn = (1.0f - z) * n + z * (bfhi_f(po0) + bflo_f(po0));
                unsigned hb = rneb(hn);
                unsigned lb = rneb(hn - __uint_as_float(hb << 16));
                astu(hout + jj * 64 + b0, (hb << 16) | lb);
            }
            {
                float r = sigm(xv1 * wir + br + sr1);
                float z = sigm(xv1 * wiz + bz + sz1);
                float n = tanhf(xv1 * win + bnx + r * (sn1 + bnh));
                float hn = (1.0f - z) * n + z * (bfhi_f(po1) + bflo_f(po1));
                unsigned hb = rneb(hn);
                unsigned lb = rneb(hn - __uint_as_float(hb << 16));
                astu(hout + jj * 64 + b0 + 1, (hb << 16) | lb);
            }
            __syncthreads();                  // drains all waves' stores
            if (tid == 0) astu(&flags[id * PADU], (unsigned)(t + 1));
        }
    } else {
        // ===================== Layer 1 (K=1024; wave w: kt = 4w..4w+3) =====================
        const int jt = id - L0WG;
        bf16x8 wA[4][3][2];
        #pragma unroll
        for (int kk = 0; kk < 4; ++kk)
            #pragma unroll
            for (int g = 0; g < 3; ++g)
                #pragma unroll
                for (int s = 0; s < 2; ++s)
                    wA[kk][g][s] = aw1f[(size_t)(((g * 32 + jt) * 32 + (4 * w + kk)) * 2 + s) * 64 + l];

        const int jj = jt * 16 + jl_e;
        const float br  = bih1[jj] + bhh1[jj];
        const float bz  = bih1[512 + jj] + bhh1[512 + jj];
        const float bnx = bih1[1024 + jj], bnh = bhh1[1024 + jj];
        const bool xside = (w < 4);

        for (int t = 1; t <= TT; ++t) {       // computes h1 state t-1
            {
                const unsigned need0 = (unsigned)t;
                const unsigned need1 = (unsigned)(t - 1);
                if (tid < 64) {
                    unsigned need = (tid == id) ? 0u : ((tid < L0WG) ? need0 : need1);
                    while (fcache < need) {
                        fcache = aldu(&flags[tid * PADU]);
                        if (fcache < need) __builtin_amdgcn_s_sleep(1);
                    }
                }
                __syncthreads();
            }
            const unsigned* y0  = r0 + ((t + 3) & 3) * HB32;   // h0 state t-1
            const unsigned* h1p = r1 + ((t + 2) & 3) * HB32;   // h1 state t-2
            unsigned*       h1o = r1 + ((t + 3) & 3) * HB32;   // h1 state t-1
            const unsigned* src = xside ? y0 : h1p;

            f32x4 acc[3][4];
            #pragma unroll
            for (int g = 0; g < 3; ++g)
                #pragma unroll
                for (int bt = 0; bt < 4; ++bt)
                    acc[g][bt] = (f32x4){0.f, 0.f, 0.f, 0.f};

            #pragma unroll
            for (int kk = 0; kk < 4; ++kk) {
                const int ktl = 4 * w + kk;               // 0..31 (frag index)
                const int ktr = xside ? ktl : (ktl - 16); // row tile within src ring
                #pragma unroll
                for (int bt = 0; bt < 4; ++bt) {
                    const unsigned* bp = src + (ktr * 32 + (l >> 4) * 8) * 64 + bt * 16 + (l & 15);
                    LOAD_B(bp)
                    #pragma unroll
                    for (int g = 0; g < 3; ++g) {
                        acc[g][bt] = MFMA16(wA[kk][g][0], Bh, acc[g][bt]);
                        acc[g][bt] = MFMA16(wA[kk][g][0], Bl, acc[g][bt]);
                        acc[g][bt] = MFMA16(wA[kk][g][1], Bh, acc[g][bt]);
                    }
                }
            }

            // reduce: waves 0-3 write r,z,nx (slots 0,1,2); waves 4-7 add r,z and
            // write nh into slot 3 (x/h n-sides kept separate).
            if (w < 4) {
                #pragma unroll
                for (int g = 0; g < 3; ++g)
                    #pragma unroll
                    for (int bt = 0; bt < 4; ++bt)
                        *(f32x4*)&red[w][g * 4 + bt][l * 4] = acc[g][bt];
            }
            __syncthreads();
            if (w >= 4) {
                const int p = w - 4;
                #pragma unroll
                for (int g = 0; g < 2; ++g)
                    #pragma unroll
                    for (int bt = 0; bt < 4; ++bt) {
                        f32x4 v = *(f32x4*)&red[p][g * 4 + bt][l * 4];
                        v += acc[g][bt];
                        *(f32x4*)&red[p][g * 4 + bt][l * 4] = v;
                    }
                #pragma unroll
                for (int bt = 0; bt < 4; ++bt)
                    *(f32x4*)&red[p][3 * 4 + bt][l * 4] = acc[2][bt];
            }
            __syncthreads();

            // epilogue
            float sr0 = 0.f, sz0 = 0.f, sx0 = 0.f, sh0 = 0.f;
            float sr1 = 0.f, sz1 = 0.f, sx1 = 0.f, sh1 = 0.f;
            #pragma unroll
            for (int p = 0; p < 4; ++p) {
                sr0 += red[p][0 * 4 + bt_e][lA * 4 + rg_e];
                sz0 += red[p][1 * 4 + bt_e][lA * 4 + rg_e];
                sx0 += red[p][2 * 4 + bt_e][lA * 4 + rg_e];
                sh0 += red[p][3 * 4 + bt_e][lA * 4 + rg_e];
                sr1 += red[p][0 * 4 + bt_e][lB * 4 + rg_e];
                sz1 += red[p][1 * 4 + bt_e][lB * 4 + rg_e];
                sx1 += red[p][2 * 4 + bt_e][lB * 4 + rg_e];
                sh1 += red[p][3 * 4 + bt_e][lB * 4 + rg_e];
            }
            unsigned po0 = aldu(h1p + jj * 64 + b0);
            unsigned po1 = aldu(h1p + jj * 64 + b0 + 1);
            {
                float r = sigm(sr0 + br);
                float z = sigm(sz0 + bz);
                float n = tanhf(sx0 + bnx + r * (sh0 + bnh));
                float hn = (1.0f - z) * n + z * (bfhi_f(po0) + bflo_f(po0));
                unsigned hb = rneb(hn);
                unsigned lb = rneb(hn - __uint_as_float(hb << 16));
                astu(h1o + jj * 64 + b0, (hb << 16) | lb);
            }
            {
                float r = sigm(sr1 + br);
                float z = sigm(sz1 + bz);
                float n = tanhf(sx1 + bnx + r * (sh1 + bnh));
                float hn = (1.0f - z) * n + z * (bfhi_f(po1) + bflo_f(po1));
                unsigned hb = rneb(hn);
                unsigned lb = rneb(hn - __uint_as_float(hb << 16));
                astu(h1o + jj * 64 + b0 + 1, (hb << 16) | lb);
            }
            __syncthreads();
            if (tid == 0) astu(&flags[id * PADU], (unsigned)t);
        }
    }
}

// out[l][b][j] = f32(ring_l[slot3][j][b])  (state 4095 in slot 3 for both rings)
__global__ __launch_bounds__(256) void copy_out_k(const unsigned* __restrict__ ws,
                                                  float* __restrict__ out) {
    int i = blockIdx.x * 256 + threadIdx.x;   // 2*64*512
    int lyr = i >> 15;
    int rem = i & 32767;
    int b = rem >> 9;
    int j = rem & 511;
    unsigned p = ws[(size_t)lyr * 4 * HB32 + 3 * HB32 + j * 64 + b];
    out[i] = bfhi_f(p) + bflo_f(p);
}

extern "C" void kernel_launch(void* const* d_in, const int* in_sizes, int n_in,
                              void* d_out, int out_size, void* d_ws, size_t ws_size,
                              hipStream_t stream)
{
    const float* x    = (const float*)d_in[0];
    const float* wih0 = (const float*)d_in[1];
    const float* whh0 = (const float*)d_in[2];
    const float* bih0 = (const float*)d_in[3];
    const float* bhh0 = (const float*)d_in[4];
    const float* wih1 = (const float*)d_in[5];
    const float* whh1 = (const float*)d_in[6];
    const float* bih1 = (const float*)d_in[7];
    const float* bhh1 = (const float*)d_in[8];
    float* out = (float*)d_out;
    unsigned* ws = (unsigned*)d_ws;

    unsigned short* aw0 = (unsigned short*)(ws + 8 * HB32 + NWG * PADU);
    unsigned short* aw1 = aw0 + (size_t)96 * 16 * 2 * 64 * 8;

    const int nzero = 8 * HB32 + NWG * PADU;
    zero_k<<<(nzero + 255) / 256, 256, 0, stream>>>(ws, nzero);
    prep_aw0<<<(96 * 16 * 2 * 64) / 256, 256, 0, stream>>>(whh0, aw0);
    prep_aw1<<<(96 * 32 * 2 * 64) / 256, 256, 0, stream>>>(wih1, whh1, aw1);
    gru_persist<<<NWG, 512, 0, stream>>>(x, wih0, bih0, bhh0, bih1, bhh1, ws);
    copy_out_k<<<(2 * BB * HH) / 256, 256, 0, stream>>>(ws, out);
}

// Round 11
// 26358.456 us; speedup vs baseline: 14.2275x; 1.1566x over previous
//
#include <hip/hip_runtime.h>
#include <math.h>

// 2-layer GRU, T=4096, B=64, H=512, input=1. Output = final hidden (2,64,512) f32.
//
// R11 = R10 (weights-in-registers bf16-split MFMA, 64 WG x 512 thr persistent,
// relaxed-agent-atomic rings/flags) with:
//  - bt-XOR swizzle on LDS reduce columns (R10: 8.2e8 bank conflicts from
//    1024B-aligned rows; (l^bt)*4 spreads bt rows across banks -> <=2-way)
//  - hold/x prefetched at iteration top (self-produced rows: no wait needed;
//    writer of state t+3/t+2 guards on this WG's unposted flag -> safe)
//  - decentralized producer waits (per wave: only its B-slice producers)
//      L0 wave w: flags[4w..4w+3] >= t
//      L1 wave w<4 (x-side): flags[8w..8w+7] >= t
//      L1 wave w>=4 (h-side): flags[32+8(w-4)..+7] >= t-1
//    + deferred ring-overwrite guard on wave 4, overlapped with reduce:
//      L0: L0 flags >= t-2 (readers of state t-4 post t-2) AND L1 >= t-3
//      L1: L1 flags >= t-3
// Rings depth 4 (state s in slot s&3). L0 posts t+1 after iter t; L1 posts t
// after iter t (computes state t-1).
// ws: ring0[4][512][64]u32 | ring1[...] | flags[64*32] | aw0 | aw1

#define TT 4096
#define BB 64
#define HH 512
#define NWG 64
#define L0WG 32
#define PADU 32
#define HB32 (HH * BB)

typedef __attribute__((ext_vector_type(8))) short bf16x8;
typedef __attribute__((ext_vector_type(4))) float f32x4;

#define MFMA16(a, b, c) __builtin_amdgcn_mfma_f32_16x16x32_bf16((a), (b), (c), 0, 0, 0)

__device__ __forceinline__ float sigm(float v) { return 1.0f / (1.0f + expf(-v)); }

__device__ __forceinline__ unsigned aldu(const unsigned* p) {
    return __hip_atomic_load((unsigned*)p, __ATOMIC_RELAXED, __HIP_MEMORY_SCOPE_AGENT);
}
__device__ __forceinline__ void astu(unsigned* p, unsigned v) {
    __hip_atomic_store(p, v, __ATOMIC_RELAXED, __HIP_MEMORY_SCOPE_AGENT);
}
__device__ __forceinline__ unsigned short rneb(float f) {   // fp32 -> bf16 RNE
    unsigned u = __float_as_uint(f);
    return (unsigned short)((u + 0x7fffu + ((u >> 16) & 1u)) >> 16);
}
__device__ __forceinline__ float bfhi_f(unsigned p) { return __uint_as_float(p & 0xffff0000u); }
__device__ __forceinline__ float bflo_f(unsigned p) { return __uint_as_float(p << 16); }

union frag_u { unsigned u[4]; bf16x8 v; };
__device__ __forceinline__ bf16x8 mkfrag(unsigned a, unsigned b, unsigned c, unsigned d) {
    frag_u x; x.u[0] = a; x.u[1] = b; x.u[2] = c; x.u[3] = d; return x.v;
}
__device__ __forceinline__ void wait_fence() {
    __builtin_amdgcn_sched_barrier(0);
    asm volatile("" ::: "memory");
}

__global__ __launch_bounds__(256) void zero_k(unsigned* p, int n) {
    int i = blockIdx.x * 256 + threadIdx.x;
    if (i < n) p[i] = 0u;
}

// A-frag prep (R9/R10 layout, verified): frag fb = ((rt*KTN + kt)*2 + split)*64 + lane,
// rt = gate*32 + jt; row = jt*16 + (lane&15); k = kt*32 + (lane>>4)*8 + i.
__global__ __launch_bounds__(256) void prep_aw0(const float* __restrict__ whh0,
                                                unsigned short* __restrict__ aw0) {
    int gid = blockIdx.x * 256 + threadIdx.x;           // 96*16*2*64
    if (gid >= 96 * 16 * 2 * 64) return;
    int lane = gid & 63, split = (gid >> 6) & 1, kt = (gid >> 7) & 15, rt = gid >> 11;
    int grow = (rt >> 5) * 512 + (rt & 31) * 16 + (lane & 15);
    int k0 = kt * 32 + (lane >> 4) * 8;
    #pragma unroll
    for (int i = 0; i < 8; ++i) {
        float val = whh0[(size_t)grow * 512 + k0 + i];
        unsigned short hb = rneb(val);
        unsigned short us = hb;
        if (split) us = rneb(val - __uint_as_float(((unsigned)hb) << 16));
        aw0[(size_t)gid * 8 + i] = us;
    }
}

__global__ __launch_bounds__(256) void prep_aw1(const float* __restrict__ wih1,
                                                const float* __restrict__ whh1,
                                                unsigned short* __restrict__ aw1) {
    int gid = blockIdx.x * 256 + threadIdx.x;           // 96*32*2*64
    if (gid >= 96 * 32 * 2 * 64) return;
    int lane = gid & 63, split = (gid >> 6) & 1, kt = (gid >> 7) & 31, rt = gid >> 12;
    int grow = (rt >> 5) * 512 + (rt & 31) * 16 + (lane & 15);
    #pragma unroll
    for (int i = 0; i < 8; ++i) {
        int k = kt * 32 + (lane >> 4) * 8 + i;
        float val = (k < 512) ? wih1[(size_t)grow * 512 + k]
                              : whh1[(size_t)grow * 512 + (k - 512)];
        unsigned short hb = rneb(val);
        unsigned short us = hb;
        if (split) us = rneb(val - __uint_as_float(((unsigned)hb) << 16));
        aw1[(size_t)gid * 8 + i] = us;
    }
}

// build Bh/Bl frags from 8 packed u32 (hi<<16|lo) at bp, bp+64, ...
#define LOAD_B(bp)                                                              \
    unsigned p0 = aldu((bp) + 0 * 64), p1 = aldu((bp) + 1 * 64);                \
    unsigned p2 = aldu((bp) + 2 * 64), p3 = aldu((bp) + 3 * 64);                \
    unsigned p4 = aldu((bp) + 4 * 64), p5 = aldu((bp) + 5 * 64);                \
    unsigned p6 = aldu((bp) + 6 * 64), p7 = aldu((bp) + 7 * 64);                \
    bf16x8 Bh = mkfrag(__builtin_amdgcn_perm(p1, p0, 0x07060302u),              \
                       __builtin_amdgcn_perm(p3, p2, 0x07060302u),              \
                       __builtin_amdgcn_perm(p5, p4, 0x07060302u),              \
                       __builtin_amdgcn_perm(p7, p6, 0x07060302u));             \
    bf16x8 Bl = mkfrag(__builtin_amdgcn_perm(p1, p0, 0x05040100u),              \
                       __builtin_amdgcn_perm(p3, p2, 0x05040100u),              \
                       __builtin_amdgcn_perm(p5, p4, 0x05040100u),              \
                       __builtin_amdgcn_perm(p7, p6, 0x05040100u));

__global__ __launch_bounds__(512, 1) void gru_persist(
    const float* __restrict__ x,
    const float* __restrict__ wih0,
    const float* __restrict__ bih0, const float* __restrict__ bhh0,
    const float* __restrict__ bih1, const float* __restrict__ bhh1,
    unsigned* __restrict__ ws)
{
    __shared__ float red[4][16][256];        // 64 KB: [pair][gate*4+bt][(l^bt)*4+rg]

    unsigned* r0 = ws;                        // [4][512][64] packed u32
    unsigned* r1 = ws + 4 * HB32;
    unsigned* flags = ws + 8 * HB32;
    const bf16x8* aw0f = (const bf16x8*)(ws + 8 * HB32 + NWG * PADU);
    const bf16x8* aw1f = aw0f + (size_t)96 * 16 * 2 * 64;

    const int tid = threadIdx.x;
    const int l   = tid & 63;
    const int w   = tid >> 6;                 // wave 0..7 = k-slice
    const int id  = blockIdx.x;

    // epilogue mapping: thread handles outputs (jl_e, b0) and (jl_e, b0+1)
    const int idx0 = tid * 2;
    const int jl_e = idx0 >> 6;               // 0..15
    const int b0   = idx0 & 63;               // even
    const int rg_e = jl_e & 3;
    const int bt_e = b0 >> 4;
    const int lA = ((jl_e >> 2) << 4) | (b0 & 15);
    const int lB = lA + 1;
    const int cA = ((lA ^ bt_e) << 2) + rg_e; // swizzled columns
    const int cB = ((lB ^ bt_e) << 2) + rg_e;

    unsigned fprod = 0;                       // cached producer flag (per lane)
    unsigned fguard = 0;                      // cached guard flag (wave 4 lanes)

    if (id < L0WG) {
        // ===================== Layer 0 (K=512; wave w: kt = 2w,2w+1) =====================
        const int jt = id;
        bf16x8 wA[2][3][2];
        #pragma unroll
        for (int kk = 0; kk < 2; ++kk)
            #pragma unroll
            for (int g = 0; g < 3; ++g)
                #pragma unroll
                for (int s = 0; s < 2; ++s)
                    wA[kk][g][s] = aw0f[(size_t)(((g * 32 + jt) * 16 + (2 * w + kk)) * 2 + s) * 64 + l];

        const int jj = jt * 16 + jl_e;
        const float wir = wih0[jj], wiz = wih0[512 + jj], win = wih0[1024 + jj];
        const float br  = bih0[jj] + bhh0[jj];
        const float bz  = bih0[512 + jj] + bhh0[512 + jj];
        const float bnx = bih0[1024 + jj], bnh = bhh0[1024 + jj];
        __syncthreads();

        for (int t = 0; t < TT; ++t) {
            const unsigned* hin  = r0 + ((t + 3) & 3) * HB32;  // state t-1
            unsigned*       hout = r0 + (t & 3) * HB32;        // state t

            // prefetch epilogue operands (own rows: self-produced, overwrite-safe)
            unsigned po0 = aldu(hin + jj * 64 + b0);
            unsigned po1 = aldu(hin + jj * 64 + b0 + 1);
            const float xv0 = x[(size_t)t * BB + b0];
            const float xv1 = x[(size_t)t * BB + b0 + 1];

            // producer wait: this wave's B-slice producers (L0 WGs 4w..4w+3)
            if (l < 4) {
                const unsigned need = (unsigned)t;
                while (fprod < need) {
                    fprod = aldu(&flags[(4 * w + l) * PADU]);
                    if (fprod < need) __builtin_amdgcn_s_sleep(1);
                }
            }
            wait_fence();

            f32x4 acc[3][4];
            #pragma unroll
            for (int g = 0; g < 3; ++g)
                #pragma unroll
                for (int bt = 0; bt < 4; ++bt)
                    acc[g][bt] = (f32x4){0.f, 0.f, 0.f, 0.f};

            #pragma unroll
            for (int kk = 0; kk < 2; ++kk) {
                const int kt = 2 * w + kk;
                #pragma unroll
                for (int bt = 0; bt < 4; ++bt) {
                    const unsigned* bp = hin + (kt * 32 + (l >> 4) * 8) * 64 + bt * 16 + (l & 15);
                    LOAD_B(bp)
                    #pragma unroll
                    for (int g = 0; g < 3; ++g) {
                        acc[g][bt] = MFMA16(wA[kk][g][0], Bh, acc[g][bt]);
                        acc[g][bt] = MFMA16(wA[kk][g][0], Bl, acc[g][bt]);
                        acc[g][bt] = MFMA16(wA[kk][g][1], Bh, acc[g][bt]);
                    }
                }
            }

            // deferred ring-overwrite guard (wave 4, overlapped with reduce):
            // L0 flags >= t-2 (lanes 0-31), L1 flags >= t-3 (lanes 32-63)
            if (w == 4) {
                const unsigned ng = (l < 32) ? ((t >= 2) ? (unsigned)(t - 2) : 0u)
                                             : ((t >= 3) ? (unsigned)(t - 3) : 0u);
                while (fguard < ng) {
                    fguard = aldu(&flags[l * PADU]);
                    if (fguard < ng) __builtin_amdgcn_s_sleep(1);
                }
            }
            wait_fence();

            // reduce round 1: waves 0-3 write (bt-XOR swizzled columns)
            if (w < 4) {
                #pragma unroll
                for (int g = 0; g < 3; ++g)
                    #pragma unroll
                    for (int bt = 0; bt < 4; ++bt)
                        *(f32x4*)&red[w][g * 4 + bt][(l ^ bt) * 4] = acc[g][bt];
            }
            __syncthreads();
            // round 2: waves 4-7 add into slots
            if (w >= 4) {
                const int p = w - 4;
                #pragma unroll
                for (int g = 0; g < 3; ++g)
                    #pragma unroll
                    for (int bt = 0; bt < 4; ++bt) {
                        f32x4 v = *(f32x4*)&red[p][g * 4 + bt][(l ^ bt) * 4];
                        v += acc[g][bt];
                        *(f32x4*)&red[p][g * 4 + bt][(l ^ bt) * 4] = v;
                    }
            }
            __syncthreads();

            // epilogue: 2 outputs (jj, b0), (jj, b0+1)
            float sr0 = 0.f, sz0 = 0.f, sn0 = 0.f, sr1 = 0.f, sz1 = 0.f, sn1 = 0.f;
            #pragma unroll
            for (int p = 0; p < 4; ++p) {
                sr0 += red[p][0 * 4 + bt_e][cA];
                sz0 += red[p][1 * 4 + bt_e][cA];
                sn0 += red[p][2 * 4 + bt_e][cA];
                sr1 += red[p][0 * 4 + bt_e][cB];
                sz1 += red[p][1 * 4 + bt_e][cB];
                sn1 += red[p][2 * 4 + bt_e][cB];
            }
            {
                float r = sigm(xv0 * wir + br + sr0);
                float z = sigm(xv0 * wiz + bz + sz0);
                float n = tanhf(xv0 * win + bnx + r * (sn0 + bnh));
                float hn = (1.0f - z) * n + z * (bfhi_f(po0) + bflo_f(po0));
                unsigned hb = rneb(hn);
                unsigned lb = rneb(hn - __uint_as_float(hb << 16));
                astu(hout + jj * 64 + b0, (hb << 16) | lb);
            }
            {
                float r = sigm(xv1 * wir + br + sr1);
                float z = sigm(xv1 * wiz + bz + sz1);
                float n = tanhf(xv1 * win + bnx + r * (sn1 + bnh));
                float hn = (1.0f - z) * n + z * (bfhi_f(po1) + bflo_f(po1));
                unsigned hb = rneb(hn);
                unsigned lb = rneb(hn - __uint_as_float(hb << 16));
                astu(hout + jj * 64 + b0 + 1, (hb << 16) | lb);
            }
            __syncthreads();                  // all waves' stores drained
            if (tid == 0) astu(&flags[id * PADU], (unsigned)(t + 1));
        }
    } else {
        // ===================== Layer 1 (K=1024; wave w: kt = 4w..4w+3) =====================
        const int jt = id - L0WG;
        bf16x8 wA[4][3][2];
        #pragma unroll
        for (int kk = 0; kk < 4; ++kk)
            #pragma unroll
            for (int g = 0; g < 3; ++g)
                #pragma unroll
                for (int s = 0; s < 2; ++s)
                    wA[kk][g][s] = aw1f[(size_t)(((g * 32 + jt) * 32 + (4 * w + kk)) * 2 + s) * 64 + l];

        const int jj = jt * 16 + jl_e;
        const float br  = bih1[jj] + bhh1[jj];
        const float bz  = bih1[512 + jj] + bhh1[512 + jj];
        const float bnx = bih1[1024 + jj], bnh = bhh1[1024 + jj];
        const bool xside = (w < 4);
        __syncthreads();

        for (int t = 1; t <= TT; ++t) {       // computes h1 state t-1
            const unsigned* y0  = r0 + ((t + 3) & 3) * HB32;   // h0 state t-1
            const unsigned* h1p = r1 + ((t + 2) & 3) * HB32;   // h1 state t-2
            unsigned*       h1o = r1 + ((t + 3) & 3) * HB32;   // h1 state t-1
            const unsigned* src = xside ? y0 : h1p;

            // prefetch epilogue operands (own rows of h1p: self-produced)
            unsigned po0 = aldu(h1p + jj * 64 + b0);
            unsigned po1 = aldu(h1p + jj * 64 + b0 + 1);

            // producer wait: x-side waves need 8 L0 flags >= t;
            // h-side waves need 8 L1 flags >= t-1
            if (l < 8) {
                unsigned need, fidx;
                if (xside) { need = (unsigned)t;       fidx = (unsigned)(8 * w + l); }
                else       { need = (unsigned)(t - 1); fidx = (unsigned)(32 + 8 * (w - 4) + l); }
                while (fprod < need) {
                    fprod = aldu(&flags[fidx * PADU]);
                    if (fprod < need) __builtin_amdgcn_s_sleep(1);
                }
            }
            wait_fence();

            f32x4 acc[3][4];
            #pragma unroll
            for (int g = 0; g < 3; ++g)
                #pragma unroll
                for (int bt = 0; bt < 4; ++bt)
                    acc[g][bt] = (f32x4){0.f, 0.f, 0.f, 0.f};

            #pragma unroll
            for (int kk = 0; kk < 4; ++kk) {
                const int ktl = 4 * w + kk;               // 0..31 (frag index)
                const int ktr = xside ? ktl : (ktl - 16); // row tile within src ring
                #pragma unroll
                for (int bt = 0; bt < 4; ++bt) {
                    const unsigned* bp = src + (ktr * 32 + (l >> 4) * 8) * 64 + bt * 16 + (l & 15);
                    LOAD_B(bp)
                    #pragma unroll
                    for (int g = 0; g < 3; ++g) {
                        acc[g][bt] = MFMA16(wA[kk][g][0], Bh, acc[g][bt]);
                        acc[g][bt] = MFMA16(wA[kk][g][0], Bl, acc[g][bt]);
                        acc[g][bt] = MFMA16(wA[kk][g][1], Bh, acc[g][bt]);
                    }
                }
            }

            // deferred ring-overwrite guard: L1 flags >= t-3 (lanes 0-31)
            if (w == 4 && l < 32) {
                const unsigned ng = (t >= 3) ? (unsigned)(t - 3) : 0u;
                while (fguard < ng) {
                    fguard = aldu(&flags[(32 + l) * PADU]);
                    if (fguard < ng) __builtin_amdgcn_s_sleep(1);
                }
            }
            wait_fence();

            // reduce: waves 0-3 write r,z,nx (slots g=0,1,2); waves 4-7 add r,z,
            // write nh into slot g=3 (x/h n-sides separate). bt-XOR swizzle.
            if (w < 4) {
                #pragma unroll
                for (int g = 0; g < 3; ++g)
                    #pragma unroll
                    for (int bt = 0; bt < 4; ++bt)
                        *(f32x4*)&red[w][g * 4 + bt][(l ^ bt) * 4] = acc[g][bt];
            }
            __syncthreads();
            if (w >= 4) {
                const int p = w - 4;
                #pragma unroll
                for (int g = 0; g < 2; ++g)
                    #pragma unroll
                    for (int bt = 0; bt < 4; ++bt) {
                        f32x4 v = *(f32x4*)&red[p][g * 4 + bt][(l ^ bt) * 4];
                        v += acc[g][bt];
                        *(f32x4*)&red[p][g * 4 + bt][(l ^ bt) * 4] = v;
                    }
                #pragma unroll
                for (int bt = 0; bt < 4; ++bt)
                    *(f32x4*)&red[p][3 * 4 + bt][(l ^ bt) * 4] = acc[2][bt];
            }
            __syncthreads();

            // epilogue
            float sr0 = 0.f, sz0 = 0.f, sx0 = 0.f, sh0 = 0.f;
            float sr1 = 0.f, sz1 = 0.f, sx1 = 0.f, sh1 = 0.f;
            #pragma unroll
            for (int p = 0; p < 4; ++p) {
                sr0 += red[p][0 * 4 + bt_e][cA];
                sz0 += red[p][1 * 4 + bt_e][cA];
                sx0 += red[p][2 * 4 + bt_e][cA];
                sh0 += red[p][3 * 4 + bt_e][cA];
                sr1 += red[p][0 * 4 + bt_e][cB];
                sz1 += red[p][1 * 4 + bt_e][cB];
                sx1 += red[p][2 * 4 + bt_e][cB];
                sh1 += red[p][3 * 4 + bt_e][cB];
            }
            {
                float r = sigm(sr0 + br);
                float z = sigm(sz0 + bz);
                float n = tanhf(sx0 + bnx + r * (sh0 + bnh));
                float hn = (1.0f - z) * n + z * (bfhi_f(po0) + bflo_f(po0));
                unsigned hb = rneb(hn);
                unsigned lb = rneb(hn - __uint_as_float(hb << 16));
                astu(h1o + jj * 64 + b0, (hb << 16) | lb);
            }
            {
                float r = sigm(sr1 + br);
                float z = sigm(sz1 + bz);
                float n = tanhf(sx1 + bnx + r * (sh1 + bnh));
                float hn = (1.0f - z) * n + z * (bfhi_f(po1) + bflo_f(po1));
                unsigned hb = rneb(hn);
                unsigned lb = rneb(hn - __uint_as_float(hb << 16));
                astu(h1o + jj * 64 + b0 + 1, (hb << 16) | lb);
            }
            __syncthreads();
            if (tid == 0) astu(&flags[id * PADU], (unsigned)t);
        }
    }
}

// out[l][b][j] = f32(ring_l[slot3][j][b])  (state 4095 in slot 3 for both rings)
__global__ __launch_bounds__(256) void copy_out_k(const unsigned* __restrict__ ws,
                                                  float* __restrict__ out) {
    int i = blockIdx.x * 256 + threadIdx.x;   // 2*64*512
    int lyr = i >> 15;
    int rem = i & 32767;
    int b = rem >> 9;
    int j = rem & 511;
    unsigned p = ws[(size_t)lyr * 4 * HB32 + 3 * HB32 + j * 64 + b];
    out[i] = bfhi_f(p) + bflo_f(p);
}

extern "C" void kernel_launch(void* const* d_in, const int* in_sizes, int n_in,
                              void* d_out, int out_size, void* d_ws, size_t ws_size,
                              hipStream_t stream)
{
    const float* x    = (const float*)d_in[0];
    const float* wih0 = (const float*)d_in[1];
    const float* whh0 = (const float*)d_in[2];
    const float* bih0 = (const float*)d_in[3];
    const float* bhh0 = (const float*)d_in[4];
    const float* wih1 = (const float*)d_in[5];
    const float* whh1 = (const float*)d_in[6];
    const float* bih1 = (const float*)d_in[7];
    const float* bhh1 = (const float*)d_in[8];
    float* out = (float*)d_out;
    unsigned* ws = (unsigned*)d_ws;

    unsigned short* aw0 = (unsigned short*)(ws + 8 * HB32 + NWG * PADU);
    unsigned short* aw1 = aw0 + (size_t)96 * 16 * 2 * 64 * 8;

    const int nzero = 8 * HB32 + NWG * PADU;
    zero_k<<<(nzero + 255) / 256, 256, 0, stream>>>(ws, nzero);
    prep_aw0<<<(96 * 16 * 2 * 64) / 256, 256, 0, stream>>>(whh0, aw0);
    prep_aw1<<<(96 * 32 * 2 * 64) / 256, 256, 0, stream>>>(wih1, whh1, aw1);
    gru_persist<<<NWG, 512, 0, stream>>>(x, wih0, bih0, bhh0, bih1, bhh1, ws);
    copy_out_k<<<(2 * BB * HH) / 256, 256, 0, stream>>>(ws, out);
}

// Round 12
// 16822.290 us; speedup vs baseline: 22.2928x; 1.5669x over previous
//
#include <hip/hip_runtime.h>
#include <math.h>

// 2-layer GRU, T=4096, B=64, H=512, input=1. Output = final hidden (2,64,512) f32.
//
// R12: load-window collapse. R11 diagnosis: ~16 serialized LLC load windows
// per step (8-load groups consumed immediately) = 4-6us/step stall. Changes:
//  - ring layout [(k>>1)][b][pair]: B-fetch = 4 x u64 relaxed-atomic loads per
//    lane per kt (native dwordx2, compiler counted waitcnts)
//  - 128 WGs: (layer, jt, b-half). Per-WG: 16 rows x 32 batch. Per-wave work
//    halves; kt loads software-pipelined via named double buffers (static
//    unroll) -> ~1-2 exposed LLC windows/step
//  - epilogue: 1 output/thread, fewer LDS reads, 1 store/thread
// Kept from R9-R11 (proven): bf16-split MFMA (Ah*Bh+Ah*Bl+Al*Bh, fp32 acc),
// A-frags resident in VGPRs, relaxed-agent-atomic rings (depth 4) + flags,
// decentralized producer waits + deferred overwrite guards, bt-XOR LDS swizzle.
// Flag algebra (wg id = layer*64 + jt*2 + bh; L0 posts t+1 after iter t, L1
// posts t after iter t which computes state t-1):
//   L0 wave w waits L0(4w+i, bh) >= t          (i=0..3)
//   L1 wave w<4 waits L0(8w+i, bh) >= t        (x-side, i=0..7)
//   L1 wave w>=4 waits L1(8(w-4)+i, bh) >= t-1 (h-side)
//   L0 guard (wave4): L0(*, bh) >= t-2 && L1(*, bh) >= t-3
//   L1 guard (wave4): L1(*, bh) >= t-3
// ws: ring0[4][512*64]u32 | ring1[...] | flags[128*32] | aw0 | aw1

#define TT 4096
#define BB 64
#define HH 512
#define NWG 128
#define PADU 32
#define HB32 (HH * BB)

typedef __attribute__((ext_vector_type(8))) short bf16x8;
typedef __attribute__((ext_vector_type(4))) float f32x4;
typedef unsigned long long ull;

#define MFMA16(a, b, c) __builtin_amdgcn_mfma_f32_16x16x32_bf16((a), (b), (c), 0, 0, 0)

__device__ __forceinline__ float sigm(float v) { return 1.0f / (1.0f + expf(-v)); }

__device__ __forceinline__ unsigned aldu(const unsigned* p) {
    return __hip_atomic_load((unsigned*)p, __ATOMIC_RELAXED, __HIP_MEMORY_SCOPE_AGENT);
}
__device__ __forceinline__ void astu(unsigned* p, unsigned v) {
    __hip_atomic_store(p, v, __ATOMIC_RELAXED, __HIP_MEMORY_SCOPE_AGENT);
}
__device__ __forceinline__ ull ald64(const ull* p) {
    return __hip_atomic_load((ull*)p, __ATOMIC_RELAXED, __HIP_MEMORY_SCOPE_AGENT);
}
__device__ __forceinline__ unsigned short rneb(float f) {   // fp32 -> bf16 RNE
    unsigned u = __float_as_uint(f);
    return (unsigned short)((u + 0x7fffu + ((u >> 16) & 1u)) >> 16);
}
__device__ __forceinline__ float bfhi_f(unsigned p) { return __uint_as_float(p & 0xffff0000u); }
__device__ __forceinline__ float bflo_f(unsigned p) { return __uint_as_float(p << 16); }

union frag_u { unsigned u[4]; bf16x8 v; };
__device__ __forceinline__ bf16x8 mkfrag(unsigned a, unsigned b, unsigned c, unsigned d) {
    frag_u x; x.u[0] = a; x.u[1] = b; x.u[2] = c; x.u[3] = d; return x.v;
}
__device__ __forceinline__ void wait_fence() {
    __builtin_amdgcn_sched_barrier(0);
    asm volatile("" ::: "memory");
}

__global__ __launch_bounds__(256) void zero_k(unsigned* p, int n) {
    int i = blockIdx.x * 256 + threadIdx.x;
    if (i < n) p[i] = 0u;
}

// A-frag prep (R9-R11 layout, verified): frag fb = ((rt*KTN + kt)*2 + split)*64 + lane,
// rt = gate*32 + jt; row = jt*16 + (lane&15); k = kt*32 + (lane>>4)*8 + i.
__global__ __launch_bounds__(256) void prep_aw0(const float* __restrict__ whh0,
                                                unsigned short* __restrict__ aw0) {
    int gid = blockIdx.x * 256 + threadIdx.x;           // 96*16*2*64
    if (gid >= 96 * 16 * 2 * 64) return;
    int lane = gid & 63, split = (gid >> 6) & 1, kt = (gid >> 7) & 15, rt = gid >> 11;
    int grow = (rt >> 5) * 512 + (rt & 31) * 16 + (lane & 15);
    int k0 = kt * 32 + (lane >> 4) * 8;
    #pragma unroll
    for (int i = 0; i < 8; ++i) {
        float val = whh0[(size_t)grow * 512 + k0 + i];
        unsigned short hb = rneb(val);
        unsigned short us = hb;
        if (split) us = rneb(val - __uint_as_float(((unsigned)hb) << 16));
        aw0[(size_t)gid * 8 + i] = us;
    }
}

__global__ __launch_bounds__(256) void prep_aw1(const float* __restrict__ wih1,
                                                const float* __restrict__ whh1,
                                                unsigned short* __restrict__ aw1) {
    int gid = blockIdx.x * 256 + threadIdx.x;           // 96*32*2*64
    if (gid >= 96 * 32 * 2 * 64) return;
    int lane = gid & 63, split = (gid >> 6) & 1, kt = (gid >> 7) & 31, rt = gid >> 12;
    int grow = (rt >> 5) * 512 + (rt & 31) * 16 + (lane & 15);
    #pragma unroll
    for (int i = 0; i < 8; ++i) {
        int k = kt * 32 + (lane >> 4) * 8 + i;
        float val = (k < 512) ? wih1[(size_t)grow * 512 + k]
                              : whh1[(size_t)grow * 512 + (k - 512)];
        unsigned short hb = rneb(val);
        unsigned short us = hb;
        if (split) us = rneb(val - __uint_as_float(((unsigned)hb) << 16));
        aw1[(size_t)gid * 8 + i] = us;
    }
}

// issue one kt's B loads: buf[btl][i] = pair (k0+2i, k0+2i+1) for batch col
// bcol0 + btl*16 ; u64 idx = (ktr*16 + (l>>4)*4 + i)*64 + col
#define ISSUE_KT(buf, src64, ktr)                                               \
    {                                                                           \
        _Pragma("unroll")                                                       \
        for (int btl = 0; btl < 2; ++btl)                                       \
            _Pragma("unroll")                                                   \
            for (int i = 0; i < 4; ++i)                                         \
                buf[btl][i] = ald64((src64) + ((ktr) * 16 + (l >> 4) * 4 + i) * 64 \
                                    + bcol0 + btl * 16);                        \
    }

#define COMPUTE_KT(buf, kk)                                                     \
    {                                                                           \
        _Pragma("unroll")                                                       \
        for (int btl = 0; btl < 2; ++btl) {                                     \
            unsigned p0 = (unsigned)buf[btl][0], p1 = (unsigned)(buf[btl][0] >> 32); \
            unsigned p2 = (unsigned)buf[btl][1], p3 = (unsigned)(buf[btl][1] >> 32); \
            unsigned p4 = (unsigned)buf[btl][2], p5 = (unsigned)(buf[btl][2] >> 32); \
            unsigned p6 = (unsigned)buf[btl][3], p7 = (unsigned)(buf[btl][3] >> 32); \
            bf16x8 Bh = mkfrag(__builtin_amdgcn_perm(p1, p0, 0x07060302u),      \
                               __builtin_amdgcn_perm(p3, p2, 0x07060302u),      \
                               __builtin_amdgcn_perm(p5, p4, 0x07060302u),      \
                               __builtin_amdgcn_perm(p7, p6, 0x07060302u));     \
            bf16x8 Bl = mkfrag(__builtin_amdgcn_perm(p1, p0, 0x05040100u),      \
                               __builtin_amdgcn_perm(p3, p2, 0x05040100u),      \
                               __builtin_amdgcn_perm(p5, p4, 0x05040100u),      \
                               __builtin_amdgcn_perm(p7, p6, 0x05040100u));     \
            _Pragma("unroll")                                                   \
            for (int g = 0; g < 3; ++g) {                                       \
                acc[g][btl] = MFMA16(wA[kk][g][0], Bh, acc[g][btl]);            \
                acc[g][btl] = MFMA16(wA[kk][g][0], Bl, acc[g][btl]);            \
                acc[g][btl] = MFMA16(wA[kk][g][1], Bh, acc[g][btl]);            \
            }                                                                   \
        }                                                                       \
    }

__global__ __launch_bounds__(512, 1) void gru_persist(
    const float* __restrict__ x,
    const float* __restrict__ wih0,
    const float* __restrict__ bih0, const float* __restrict__ bhh0,
    const float* __restrict__ bih1, const float* __restrict__ bhh1,
    unsigned* __restrict__ ws)
{
    __shared__ float red[4][8][256];          // 32 KB: [pair][gate*2+btl][(l^btl)*4+rg]

    unsigned* r0 = ws;                        // [4][HB32] packed u32, idx=((k>>1)*64+b)*2+(k&1)
    unsigned* r1 = ws + 4 * HB32;
    unsigned* flags = ws + 8 * HB32;
    const bf16x8* aw0f = (const bf16x8*)(ws + 8 * HB32 + NWG * PADU);
    const bf16x8* aw1f = aw0f + (size_t)96 * 16 * 2 * 64;

    const int tid = threadIdx.x;
    const int l   = tid & 63;
    const int w   = tid >> 6;                 // wave 0..7 = k-slice
    const int id  = blockIdx.x;               // 0..127
    const int layer = id >> 6;
    const int jt  = (id >> 1) & 31;
    const int bh  = id & 1;                   // batch half
    const int bcol0 = bh * 32 + (l & 15);     // base batch col for B loads

    // epilogue mapping: 1 output/thread: (jl_e, b_e)
    const int jl_e = tid >> 5;                // 0..15
    const int ne   = tid & 31;
    const int b_e  = bh * 32 + ne;
    const int btl_e = ne >> 4;
    const int rg_e = jl_e & 3;
    const int l_e  = ((jl_e >> 2) << 4) | (ne & 15);
    const int c_e  = ((l_e ^ btl_e) << 2) + rg_e;
    const int jj   = jt * 16 + jl_e;
    const int hidx = ((jj >> 1) * 64 + b_e) * 2 + (jj & 1);   // packed h element

    unsigned fprod = 0, fguard = 0;           // per-lane monotone flag caches

    if (layer == 0) {
        // ===================== Layer 0 (K=512; wave w: kt = 2w, 2w+1) ==========
        bf16x8 wA[2][3][2];
        #pragma unroll
        for (int kk = 0; kk < 2; ++kk)
            #pragma unroll
            for (int g = 0; g < 3; ++g)
                #pragma unroll
                for (int s = 0; s < 2; ++s)
                    wA[kk][g][s] = aw0f[(size_t)(((g * 32 + jt) * 16 + (2 * w + kk)) * 2 + s) * 64 + l];

        const float wir = wih0[jj], wiz = wih0[512 + jj], win = wih0[1024 + jj];
        const float br  = bih0[jj] + bhh0[jj];
        const float bz  = bih0[512 + jj] + bhh0[512 + jj];
        const float bnx = bih0[1024 + jj], bnh = bhh0[1024 + jj];

        for (int t = 0; t < TT; ++t) {
            const unsigned* hin  = r0 + ((t + 3) & 3) * HB32;  // state t-1
            unsigned*       hout = r0 + (t & 3) * HB32;        // state t
            const ull* hin64 = (const ull*)hin;

            unsigned po = aldu(hin + hidx);                    // self rows: no wait
            const float xv = x[(size_t)t * BB + b_e];

            if (l < 4) {                                       // producers: L0(4w+l, bh) >= t
                const unsigned need = (unsigned)t;
                while (fprod < need) {
                    fprod = aldu(&flags[((4 * w + l) * 2 + bh) * PADU]);
                    if (fprod < need) __builtin_amdgcn_s_sleep(1);
                }
            }
            wait_fence();

            f32x4 acc[3][2];
            #pragma unroll
            for (int g = 0; g < 3; ++g)
                #pragma unroll
                for (int btl = 0; btl < 2; ++btl)
                    acc[g][btl] = (f32x4){0.f, 0.f, 0.f, 0.f};

            ull bbA[2][4], bbB[2][4];
            ISSUE_KT(bbA, hin64, 2 * w)
            ISSUE_KT(bbB, hin64, 2 * w + 1)
            COMPUTE_KT(bbA, 0)
            COMPUTE_KT(bbB, 1)

            // deferred overwrite guard (wave 4): L0(*,bh)>=t-2, L1(*,bh)>=t-3
            if (w == 4) {
                unsigned ng; int fidx;
                if (l < 32) { ng = (t >= 2) ? (unsigned)(t - 2) : 0u; fidx = l * 2 + bh; }
                else        { ng = (t >= 3) ? (unsigned)(t - 3) : 0u; fidx = 64 + (l - 32) * 2 + bh; }
                while (fguard < ng) {
                    fguard = aldu(&flags[fidx * PADU]);
                    if (fguard < ng) __builtin_amdgcn_s_sleep(1);
                }
            }
            wait_fence();

            if (w < 4) {
                #pragma unroll
                for (int g = 0; g < 3; ++g)
                    #pragma unroll
                    for (int btl = 0; btl < 2; ++btl)
                        *(f32x4*)&red[w][g * 2 + btl][(l ^ btl) * 4] = acc[g][btl];
            }
            __syncthreads();
            if (w >= 4) {
                const int p = w - 4;
                #pragma unroll
                for (int g = 0; g < 3; ++g)
                    #pragma unroll
                    for (int btl = 0; btl < 2; ++btl) {
                        f32x4 v = *(f32x4*)&red[p][g * 2 + btl][(l ^ btl) * 4];
                        v += acc[g][btl];
                        *(f32x4*)&red[p][g * 2 + btl][(l ^ btl) * 4] = v;
                    }
            }
            __syncthreads();

            float sr = 0.f, sz = 0.f, sn = 0.f;
            #pragma unroll
            for (int p = 0; p < 4; ++p) {
                sr += red[p][0 * 2 + btl_e][c_e];
                sz += red[p][1 * 2 + btl_e][c_e];
                sn += red[p][2 * 2 + btl_e][c_e];
            }
            {
                float r = sigm(xv * wir + br + sr);
                float z = sigm(xv * wiz + bz + sz);
                float n = tanhf(xv * win + bnx + r * (sn + bnh));
                float hn = (1.0f - z) * n + z * (bfhi_f(po) + bflo_f(po));
                unsigned hb = rneb(hn);
                unsigned lb = rneb(hn - __uint_as_float(hb << 16));
                astu(hout + hidx, (hb << 16) | lb);
            }
            __syncthreads();                  // all threads' stores drained
            if (tid == 0) astu(&flags[id * PADU], (unsigned)(t + 1));
        }
    } else {
        // ===================== Layer 1 (K=1024; wave w: ktl = 4w..4w+3) ========
        bf16x8 wA[4][3][2];
        #pragma unroll
        for (int kk = 0; kk < 4; ++kk)
            #pragma unroll
            for (int g = 0; g < 3; ++g)
                #pragma unroll
                for (int s = 0; s < 2; ++s)
                    wA[kk][g][s] = aw1f[(size_t)(((g * 32 + jt) * 32 + (4 * w + kk)) * 2 + s) * 64 + l];

        const float br  = bih1[jj] + bhh1[jj];
        const float bz  = bih1[512 + jj] + bhh1[512 + jj];
        const float bnx = bih1[1024 + jj], bnh = bhh1[1024 + jj];
        const bool xside = (w < 4);

        for (int t = 1; t <= TT; ++t) {       // computes h1 state t-1
            const unsigned* y0  = r0 + ((t + 3) & 3) * HB32;   // h0 state t-1
            const unsigned* h1p = r1 + ((t + 2) & 3) * HB32;   // h1 state t-2
            unsigned*       h1o = r1 + ((t + 3) & 3) * HB32;   // h1 state t-1
            const ull* src64 = (const ull*)(xside ? y0 : h1p);
            const int kb = xside ? (4 * w) : (4 * (w - 4));    // ring kt base

            unsigned po = aldu(h1p + hidx);                    // self rows

            if (l < 8) {
                unsigned need; int fidx;
                if (xside) { need = (unsigned)t;       fidx = (8 * w + l) * 2 + bh; }
                else       { need = (unsigned)(t - 1); fidx = 64 + (8 * (w - 4) + l) * 2 + bh; }
                while (fprod < need) {
                    fprod = aldu(&flags[fidx * PADU]);
                    if (fprod < need) __builtin_amdgcn_s_sleep(1);
                }
            }
            wait_fence();

            f32x4 acc[3][2];
            #pragma unroll
            for (int g = 0; g < 3; ++g)
                #pragma unroll
                for (int btl = 0; btl < 2; ++btl)
                    acc[g][btl] = (f32x4){0.f, 0.f, 0.f, 0.f};

            ull bbA[2][4], bbB[2][4];
            ISSUE_KT(bbA, src64, kb + 0)
            ISSUE_KT(bbB, src64, kb + 1)
            COMPUTE_KT(bbA, 0)
            ISSUE_KT(bbA, src64, kb + 2)
            COMPUTE_KT(bbB, 1)
            ISSUE_KT(bbB, src64, kb + 3)
            COMPUTE_KT(bbA, 2)
            COMPUTE_KT(bbB, 3)

            // deferred overwrite guard (wave 4): L1(*,bh) >= t-3
            if (w == 4 && l < 32) {
                const unsigned ng = (t >= 3) ? (unsigned)(t - 3) : 0u;
                while (fguard < ng) {
                    fguard = aldu(&flags[(64 + l * 2 + bh) * PADU]);
                    if (fguard < ng) __builtin_amdgcn_s_sleep(1);
                }
            }
            wait_fence();

            // reduce: waves 0-3 write r,z,nx (g-slots 0,1,2); waves 4-7 add r,z
            // and write nh into slot 3 (x/h n-sides separate)
            if (w < 4) {
                #pragma unroll
                for (int g = 0; g < 3; ++g)
                    #pragma unroll
                    for (int btl = 0; btl < 2; ++btl)
                        *(f32x4*)&red[w][g * 2 + btl][(l ^ btl) * 4] = acc[g][btl];
            }
            __syncthreads();
            if (w >= 4) {
                const int p = w - 4;
                #pragma unroll
                for (int g = 0; g < 2; ++g)
                    #pragma unroll
                    for (int btl = 0; btl < 2; ++btl) {
                        f32x4 v = *(f32x4*)&red[p][g * 2 + btl][(l ^ btl) * 4];
                        v += acc[g][btl];
                        *(f32x4*)&red[p][g * 2 + btl][(l ^ btl) * 4] = v;
                    }
                #pragma unroll
                for (int btl = 0; btl < 2; ++btl)
                    *(f32x4*)&red[p][3 * 2 + btl][(l ^ btl) * 4] = acc[2][btl];
            }
            __syncthreads();

            float sr = 0.f, sz = 0.f, sx = 0.f, sh = 0.f;
            #pragma unroll
            for (int p = 0; p < 4; ++p) {
                sr += red[p][0 * 2 + btl_e][c_e];
                sz += red[p][1 * 2 + btl_e][c_e];
                sx += red[p][2 * 2 + btl_e][c_e];
                sh += red[p][3 * 2 + btl_e][c_e];
            }
            {
                float r = sigm(sr + br);
                float z = sigm(sz + bz);
                float n = tanhf(sx + bnx + r * (sh + bnh));
                float hn = (1.0f - z) * n + z * (bfhi_f(po) + bflo_f(po));
                unsigned hb = rneb(hn);
                unsigned lb = rneb(hn - __uint_as_float(hb << 16));
                astu(h1o + hidx, (hb << 16) | lb);
            }
            __syncthreads();
            if (tid == 0) astu(&flags[id * PADU], (unsigned)t);
        }
    }
}

// out[lyr][b][j] = f32(ring_lyr[slot3][...]) ; idx = ((j>>1)*64+b)*2+(j&1)
__global__ __launch_bounds__(256) void copy_out_k(const unsigned* __restrict__ ws,
                                                  float* __restrict__ out) {
    int i = blockIdx.x * 256 + threadIdx.x;   // 2*64*512
    int lyr = i >> 15;
    int rem = i & 32767;
    int b = rem >> 9;
    int j = rem & 511;
    unsigned p = ws[(size_t)lyr * 4 * HB32 + 3 * HB32 + ((j >> 1) * 64 + b) * 2 + (j & 1)];
    out[i] = bfhi_f(p) + bflo_f(p);
}

extern "C" void kernel_launch(void* const* d_in, const int* in_sizes, int n_in,
                              void* d_out, int out_size, void* d_ws, size_t ws_size,
                              hipStream_t stream)
{
    const float* x    = (const float*)d_in[0];
    const float* wih0 = (const float*)d_in[1];
    const float* whh0 = (const float*)d_in[2];
    const float* bih0 = (const float*)d_in[3];
    const float* bhh0 = (const float*)d_in[4];
    const float* wih1 = (const float*)d_in[5];
    const float* whh1 = (const float*)d_in[6];
    const float* bih1 = (const float*)d_in[7];
    const float* bhh1 = (const float*)d_in[8];
    float* out = (float*)d_out;
    unsigned* ws = (unsigned*)d_ws;

    unsigned short* aw0 = (unsigned short*)(ws + 8 * HB32 + NWG * PADU);
    unsigned short* aw1 = aw0 + (size_t)96 * 16 * 2 * 64 * 8;

    const int nzero = 8 * HB32 + NWG * PADU;
    zero_k<<<(nzero + 255) / 256, 256, 0, stream>>>(ws, nzero);
    prep_aw0<<<(96 * 16 * 2 * 64) / 256, 256, 0, stream>>>(whh0, aw0);
    prep_aw1<<<(96 * 32 * 2 * 64) / 256, 256, 0, stream>>>(wih1, whh1, aw1);
    gru_persist<<<NWG, 512, 0, stream>>>(x, wih0, bih0, bhh0, bih1, bhh1, ws);
    copy_out_k<<<(2 * BB * HH) / 256, 256, 0, stream>>>(ws, out);
}